// Round 1
// baseline (2404.124 us; speedup 1.0000x reference)
//
#include <hip/hip_runtime.h>
#include <math.h>

// Problem constants (fixed by the harness / reference setup_inputs)
#define HH 16
#define BB 4
#define LL 4096
#define DD 1024
#define DK 64
#define MMF 256          // number of random features m
#define EPSF 1e-6f
#define DK4INV 0.35355339059327373f   // 64^-0.25 folded into orf at load

// ---------------------------------------------------------------------------
// GEMM: C[M,N] = A[M,K] @ W[N,K]^T + bias[N]
// BM=128, BN=64, BK=16, 256 threads, 8x4 micro-tile per thread. fp32.
// ---------------------------------------------------------------------------
__global__ __launch_bounds__(256) void gemm_bt(
    const float* __restrict__ A, const float* __restrict__ W,
    const float* __restrict__ bias, float* __restrict__ C,
    int M, int N, int K) {
  __shared__ float As[16][132];   // [k][m], padded: 132 -> 2-way max on stores
  __shared__ float Bs[16][68];    // [k][n]
  const int t  = threadIdx.x;
  const int tx = t & 15, ty = t >> 4;
  const int m0 = blockIdx.x * 128, n0 = blockIdx.y * 64;
  const int arow = t >> 2, aq = (t & 3) << 2;

  float acc[8][4] = {};

  for (int k0 = 0; k0 < K; k0 += 16) {
    // stage A tile (transposed to k-major) : rows m0..+127, cols k0..+15
#pragma unroll
    for (int r = 0; r < 2; ++r) {
      int row = arow + r * 64;
      float4 v = *(const float4*)&A[(size_t)(m0 + row) * K + k0 + aq];
      As[aq + 0][row] = v.x; As[aq + 1][row] = v.y;
      As[aq + 2][row] = v.z; As[aq + 3][row] = v.w;
    }
    {  // stage W tile: rows n0..+63, cols k0..+15
      float4 v = *(const float4*)&W[(size_t)(n0 + arow) * K + k0 + aq];
      Bs[aq + 0][arow] = v.x; Bs[aq + 1][arow] = v.y;
      Bs[aq + 2][arow] = v.z; Bs[aq + 3][arow] = v.w;
    }
    __syncthreads();
#pragma unroll
    for (int kk = 0; kk < 16; ++kk) {
      float a[8], b[4];
      *(float4*)&a[0] = *(const float4*)&As[kk][ty * 8];
      *(float4*)&a[4] = *(const float4*)&As[kk][ty * 8 + 4];
      *(float4*)&b[0] = *(const float4*)&Bs[kk][tx * 4];
#pragma unroll
      for (int i = 0; i < 8; ++i)
#pragma unroll
        for (int j = 0; j < 4; ++j)
          acc[i][j] += a[i] * b[j];
    }
    __syncthreads();
  }

  float4 bv = *(const float4*)&bias[n0 + tx * 4];
#pragma unroll
  for (int i = 0; i < 8; ++i) {
    float4 o;
    o.x = acc[i][0] + bv.x; o.y = acc[i][1] + bv.y;
    o.z = acc[i][2] + bv.z; o.w = acc[i][3] + bv.w;
    *(float4*)&C[(size_t)(m0 + ty * 8 + i) * N + n0 + tx * 4] = o;
  }
}

// ---------------------------------------------------------------------------
// Fused k_phi + kv + ksum.
// grid = (B*H, m/64). Block streams L in 64-row chunks, computes
// phi(k) = exp(k.orf * dk^-.25 - |k|^2/16) + eps on the fly, accumulates
// kv[m,d] (4x4 per thread) and ksum[m] in registers. 1/sqrt(m) omitted
// (cancels exactly in num/den).
// ---------------------------------------------------------------------------
__global__ __launch_bounds__(256) void kv_kernel(
    const float* __restrict__ kbuf, const float* __restrict__ vbuf,
    const float* __restrict__ orf, float* __restrict__ kv_g,
    float* __restrict__ ksum_g) {
  __shared__ float orfT[64][68];  // [kk][m]  pre-scaled by DK4INV
  __shared__ float ksT[64][68];   // [kk][l]
  __shared__ float vs[64][68];    // [l][d]
  __shared__ float kphi[64][68];  // [l][m]
  __shared__ float norms[64];
  const int t  = threadIdx.x;
  const int tx = t & 15, ty = t >> 4;
  const int bh = blockIdx.x, mt = blockIdx.y;
  const int b = bh >> 4, h = bh & 15;
  const int m0 = mt * 64;

  for (int e = t; e < 1024; e += 256) {
    int r = e >> 4, qd = (e & 15) << 2;
    float4 v = *(const float4*)&orf[(size_t)(m0 + r) * DK + qd];
    orfT[qd + 0][r] = v.x * DK4INV; orfT[qd + 1][r] = v.y * DK4INV;
    orfT[qd + 2][r] = v.z * DK4INV; orfT[qd + 3][r] = v.w * DK4INV;
  }

  float kvacc[4][4] = {};   // [j: m][i: d]
  float ksacc[4]    = {};
  const float* kb = kbuf + (size_t)b * LL * DD + h * 64;
  const float* vb = vbuf + (size_t)b * LL * DD + h * 64;

  for (int l0 = 0; l0 < LL; l0 += 64) {
    __syncthreads();   // protect previous chunk's readers
    for (int e = t; e < 1024; e += 256) {
      int r = e >> 4, qd = (e & 15) << 2;
      float4 v = *(const float4*)&kb[(size_t)(l0 + r) * DD + qd];
      ksT[qd + 0][r] = v.x; ksT[qd + 1][r] = v.y;
      ksT[qd + 2][r] = v.z; ksT[qd + 3][r] = v.w;
      float4 w = *(const float4*)&vb[(size_t)(l0 + r) * DD + qd];
      *(float4*)&vs[r][qd] = w;
    }
    __syncthreads();
    if (t < 64) {
      float s = 0.f;
      for (int kk = 0; kk < 64; ++kk) { float x = ksT[kk][t]; s += x * x; }
      norms[t] = s * 0.0625f;          // 1/(2*sqrt(dk)) = 1/16
    }
    __syncthreads();

    // projection: thread computes phi for l = 4tx+i, m = m0 + 4ty+j
    float pacc[4][4] = {};
    for (int kk = 0; kk < 64; ++kk) {
      float a[4], c[4];
      *(float4*)a = *(const float4*)&ksT[kk][tx * 4];
      *(float4*)c = *(const float4*)&orfT[kk][ty * 4];
#pragma unroll
      for (int i = 0; i < 4; ++i)
#pragma unroll
        for (int j = 0; j < 4; ++j)
          pacc[i][j] += a[i] * c[j];
    }
#pragma unroll
    for (int i = 0; i < 4; ++i) {
      float nrm = norms[tx * 4 + i];
      float4 o;
      o.x = __expf(pacc[i][0] - nrm) + EPSF;
      o.y = __expf(pacc[i][1] - nrm) + EPSF;
      o.z = __expf(pacc[i][2] - nrm) + EPSF;
      o.w = __expf(pacc[i][3] - nrm) + EPSF;
      *(float4*)&kphi[tx * 4 + i][ty * 4] = o;
    }
    __syncthreads();

    // kv accumulation: thread owns m = 4ty+j, d = 4tx+i
    for (int l = 0; l < 64; ++l) {
      float a[4], c[4];
      *(float4*)a = *(const float4*)&kphi[l][ty * 4];
      *(float4*)c = *(const float4*)&vs[l][tx * 4];
#pragma unroll
      for (int j = 0; j < 4; ++j) {
        ksacc[j] += a[j];
#pragma unroll
        for (int i = 0; i < 4; ++i)
          kvacc[j][i] += a[j] * c[i];
      }
    }
  }

#pragma unroll
  for (int j = 0; j < 4; ++j) {
    float4 o;
    o.x = kvacc[j][0]; o.y = kvacc[j][1]; o.z = kvacc[j][2]; o.w = kvacc[j][3];
    *(float4*)&kv_g[((size_t)bh * MMF + m0 + ty * 4 + j) * DK + tx * 4] = o;
  }
  if (tx == 0) {
#pragma unroll
    for (int j = 0; j < 4; ++j)
      ksum_g[(size_t)bh * MMF + m0 + ty * 4 + j] = ksacc[j];
  }
}

// ---------------------------------------------------------------------------
// Fused q_phi + num/den -> attn (pre-Wo). grid = (B*H, L/64).
// attn may alias qbuf: the block's q rows are staged into LDS before any
// global write, and other blocks touch disjoint rows/columns.
// ---------------------------------------------------------------------------
__global__ __launch_bounds__(256) void qattn_kernel(
    const float* qbuf, const float* __restrict__ orf,
    const float* __restrict__ kv_g, const float* __restrict__ ksum_g,
    float* attn) {
  __shared__ float orfT[64][68];
  __shared__ float qsT[64][68];    // [kk][l]
  __shared__ float qphiT[64][68];  // [m][l]
  __shared__ float kvs[64][68];    // [mm][d]
  __shared__ float ksums[64];
  __shared__ float norms[64];
  const int t  = threadIdx.x;
  const int tx = t & 15, ty = t >> 4;
  const int bh = blockIdx.x;
  const int b = bh >> 4, h = bh & 15;
  const int l0 = blockIdx.y * 64;
  const float* qb = qbuf + (size_t)b * LL * DD + (size_t)l0 * DD + h * 64;

  for (int e = t; e < 1024; e += 256) {
    int r = e >> 4, qd = (e & 15) << 2;
    float4 v = *(const float4*)&qb[(size_t)r * DD + qd];
    qsT[qd + 0][r] = v.x; qsT[qd + 1][r] = v.y;
    qsT[qd + 2][r] = v.z; qsT[qd + 3][r] = v.w;
  }
  __syncthreads();
  if (t < 64) {
    float s = 0.f;
    for (int kk = 0; kk < 64; ++kk) { float x = qsT[kk][t]; s += x * x; }
    norms[t] = s * 0.0625f;
  }

  float num[4][4] = {};   // [i: l][j: d]
  float den[4]    = {};

  for (int mt = 0; mt < 4; ++mt) {
    __syncthreads();      // also publishes norms on first iteration
    const int m0 = mt * 64;
    for (int e = t; e < 1024; e += 256) {
      int r = e >> 4, qd = (e & 15) << 2;
      float4 v = *(const float4*)&orf[(size_t)(m0 + r) * DK + qd];
      orfT[qd + 0][r] = v.x * DK4INV; orfT[qd + 1][r] = v.y * DK4INV;
      orfT[qd + 2][r] = v.z * DK4INV; orfT[qd + 3][r] = v.w * DK4INV;
      *(float4*)&kvs[r][qd] =
          *(const float4*)&kv_g[((size_t)bh * MMF + m0 + r) * DK + qd];
    }
    if (t < 64) ksums[t] = ksum_g[(size_t)bh * MMF + m0 + t];
    __syncthreads();

    // projection: thread -> l = 4tx+i, m = 4ty+j ; store transposed [m][l]
    float pacc[4][4] = {};
    for (int kk = 0; kk < 64; ++kk) {
      float a[4], c[4];
      *(float4*)a = *(const float4*)&qsT[kk][tx * 4];
      *(float4*)c = *(const float4*)&orfT[kk][ty * 4];
#pragma unroll
      for (int i = 0; i < 4; ++i)
#pragma unroll
        for (int j = 0; j < 4; ++j)
          pacc[i][j] += a[i] * c[j];
    }
#pragma unroll
    for (int j = 0; j < 4; ++j) {
      float4 o;
      o.x = __expf(pacc[0][j] - norms[tx * 4 + 0]) + EPSF;
      o.y = __expf(pacc[1][j] - norms[tx * 4 + 1]) + EPSF;
      o.z = __expf(pacc[2][j] - norms[tx * 4 + 2]) + EPSF;
      o.w = __expf(pacc[3][j] - norms[tx * 4 + 3]) + EPSF;
      *(float4*)&qphiT[ty * 4 + j][tx * 4] = o;
    }
    __syncthreads();

    // num/den: thread -> l = 4ty+i, d = 4tx+j
    for (int mm = 0; mm < 64; ++mm) {
      float a[4], c[4];
      *(float4*)a = *(const float4*)&qphiT[mm][ty * 4];
      *(float4*)c = *(const float4*)&kvs[mm][tx * 4];
      float ks = ksums[mm];
#pragma unroll
      for (int i = 0; i < 4; ++i) {
        den[i] += a[i] * ks;
#pragma unroll
        for (int j = 0; j < 4; ++j)
          num[i][j] += a[i] * c[j];
      }
    }
  }

  float* ab = attn + (size_t)b * LL * DD + (size_t)l0 * DD + h * 64;
#pragma unroll
  for (int i = 0; i < 4; ++i) {
    float inv = 1.0f / den[i];
    float4 o;
    o.x = num[i][0] * inv; o.y = num[i][1] * inv;
    o.z = num[i][2] * inv; o.w = num[i][3] * inv;
    *(float4*)&ab[(size_t)(ty * 4 + i) * DD + tx * 4] = o;
  }
}

// ---------------------------------------------------------------------------
extern "C" void kernel_launch(void* const* d_in, const int* in_sizes, int n_in,
                              void* d_out, int out_size, void* d_ws, size_t ws_size,
                              hipStream_t stream) {
  (void)in_sizes; (void)n_in; (void)out_size; (void)ws_size;
  const float* x   = (const float*)d_in[0];
  const float* Wq  = (const float*)d_in[1];
  const float* bq  = (const float*)d_in[2];
  const float* Wk  = (const float*)d_in[3];
  const float* bk  = (const float*)d_in[4];
  const float* Wv  = (const float*)d_in[5];
  const float* bv  = (const float*)d_in[6];
  const float* Wo  = (const float*)d_in[7];
  const float* bo  = (const float*)d_in[8];
  const float* orf = (const float*)d_in[9];
  float* out = (float*)d_out;
  float* ws  = (float*)d_ws;

  const size_t NTOK = (size_t)BB * LL;          // 16384
  float* qbuf = ws;                              // 67 MB (also reused as attn)
  float* kbuf = qbuf + NTOK * DD;                // 67 MB
  float* vbuf = kbuf + NTOK * DD;                // 67 MB
  float* kv   = vbuf + NTOK * DD;                // 16.8 MB
  float* ksum = kv + (size_t)BB * HH * MMF * DK; // 64 KB
  // total ws: ~218 MB

  dim3 gg(128, 16), gb(256);
  gemm_bt<<<gg, gb, 0, stream>>>(x, Wq, bq, qbuf, (int)NTOK, DD, DD);
  gemm_bt<<<gg, gb, 0, stream>>>(x, Wk, bk, kbuf, (int)NTOK, DD, DD);
  gemm_bt<<<gg, gb, 0, stream>>>(x, Wv, bv, vbuf, (int)NTOK, DD, DD);
  kv_kernel<<<dim3(64, 4), 256, 0, stream>>>(kbuf, vbuf, orf, kv, ksum);
  qattn_kernel<<<dim3(64, 64), 256, 0, stream>>>(qbuf, orf, kv, ksum, qbuf);
  gemm_bt<<<gg, gb, 0, stream>>>(qbuf, Wo, bo, out, (int)NTOK, DD, DD);
}

// Round 2
// 452.071 us; speedup vs baseline: 5.3180x; 5.3180x over previous
//
#include <hip/hip_runtime.h>
#include <math.h>

// Problem constants
#define HH 16
#define BB 4
#define LL 4096
#define DD 1024
#define DK 64
#define MMF 256
#define EPSF 1e-6f
#define DK4INV 0.35355339059327373f   // 64^-0.25, folded into orf
#define NSPLIT 8
#define LCH (LL / NSPLIT)             // 512 rows of L per kv block

typedef __attribute__((ext_vector_type(8))) short bf16x8;
typedef __attribute__((ext_vector_type(4))) float f32x4;

__device__ __forceinline__ unsigned short f2bf(float f) {
  union { float f; unsigned u; } v; v.f = f;
  unsigned r = v.u + 0x7FFF + ((v.u >> 16) & 1);   // RNE
  return (unsigned short)(r >> 16);
}
__device__ __forceinline__ float bf2f(unsigned short h) {
  union { unsigned u; float f; } v; v.u = ((unsigned)h) << 16;
  return v.f;
}
__device__ __forceinline__ f32x4 mfma16(bf16x8 a, bf16x8 b, f32x4 c) {
  return __builtin_amdgcn_mfma_f32_16x16x32_bf16(a, b, c, 0, 0, 0);
}

// ---------------------------------------------------------------------------
// fp32 -> bf16 conversion (n multiple of 4)
// ---------------------------------------------------------------------------
__global__ __launch_bounds__(256) void cvt_bf16(
    const float* __restrict__ src, unsigned short* __restrict__ dst, int n) {
  int i = (blockIdx.x * 256 + threadIdx.x) * 4;
  if (i < n) {
    float4 v = *(const float4*)&src[i];
    ushort4 o;
    o.x = f2bf(v.x); o.y = f2bf(v.y); o.z = f2bf(v.z); o.w = f2bf(v.w);
    *(ushort4*)&dst[i] = o;
  }
}

// orf: scale by DK4INV, split hi/lo bf16
__global__ __launch_bounds__(256) void cvt_orf(
    const float* __restrict__ src, unsigned short* __restrict__ hi,
    unsigned short* __restrict__ lo, int n) {
  int i = blockIdx.x * 256 + threadIdx.x;
  if (i < n) {
    float f = src[i] * DK4INV;
    unsigned short h = f2bf(f);
    hi[i] = h;
    lo[i] = f2bf(f - bf2f(h));
  }
}

// ---------------------------------------------------------------------------
// bf16 MFMA GEMM: C[M,N] = A[M,K] @ W[N,K]^T + bias.  128x128 tile, BK=64,
// 256 thr = 4 waves (2x2), each wave 64x64 = 4x4 frags of 16x16x32.
// OBF=1 -> bf16 output, else fp32.
// ---------------------------------------------------------------------------
template <int OBF>
__global__ __launch_bounds__(256) void gemm_mfma(
    const unsigned short* __restrict__ A, const unsigned short* __restrict__ W,
    const float* __restrict__ bias, float* __restrict__ Cf,
    unsigned short* __restrict__ Cb, int M, int N, int K) {
  __shared__ __align__(16) unsigned short As[128 * 64];
  __shared__ __align__(16) unsigned short Bs[128 * 64];
  const int tid = threadIdx.x, lane = tid & 63;
  const int w = tid >> 6, wr = w >> 1, wc = w & 1;
  const int g = lane >> 4, li = lane & 15;
  const int m0 = blockIdx.x * 128, n0 = blockIdx.y * 128;

  f32x4 acc[4][4] = {};
  const int srow = tid >> 3;         // 0..31
  const int scol = (tid & 7) * 8;    // element col (0..56 step 8)

  const unsigned short* Ab = A + (size_t)m0 * K;
  const unsigned short* Wb = W + (size_t)n0 * K;
  bf16x8 ra[4], rb[4];
#pragma unroll
  for (int s = 0; s < 4; ++s) {
    ra[s] = *(const bf16x8*)&Ab[(size_t)(s * 32 + srow) * K + scol];
    rb[s] = *(const bf16x8*)&Wb[(size_t)(s * 32 + srow) * K + scol];
  }

  for (int k0 = 0; k0 < K; k0 += 64) {
    __syncthreads();
#pragma unroll
    for (int s = 0; s < 4; ++s) {
      *(bf16x8*)&As[(s * 32 + srow) * 64 + scol] = ra[s];
      *(bf16x8*)&Bs[(s * 32 + srow) * 64 + scol] = rb[s];
    }
    __syncthreads();
    if (k0 + 64 < K) {
#pragma unroll
      for (int s = 0; s < 4; ++s) {
        ra[s] = *(const bf16x8*)&Ab[(size_t)(s * 32 + srow) * K + k0 + 64 + scol];
        rb[s] = *(const bf16x8*)&Wb[(size_t)(s * 32 + srow) * K + k0 + 64 + scol];
      }
    }
#pragma unroll
    for (int kk = 0; kk < 2; ++kk) {
      bf16x8 af[4], bfr[4];
#pragma unroll
      for (int i = 0; i < 4; ++i)
        af[i] = *(const bf16x8*)&As[(wr * 64 + i * 16 + li) * 64 + kk * 32 + g * 8];
#pragma unroll
      for (int j = 0; j < 4; ++j)
        bfr[j] = *(const bf16x8*)&Bs[(wc * 64 + j * 16 + li) * 64 + kk * 32 + g * 8];
#pragma unroll
      for (int i = 0; i < 4; ++i)
#pragma unroll
        for (int j = 0; j < 4; ++j)
          acc[i][j] = mfma16(af[i], bfr[j], acc[i][j]);
    }
  }
#pragma unroll
  for (int i = 0; i < 4; ++i) {
    const int rr = m0 + wr * 64 + i * 16 + 4 * g;
#pragma unroll
    for (int j = 0; j < 4; ++j) {
      const int cc = n0 + wc * 64 + j * 16 + li;
      const float bz = bias[cc];
#pragma unroll
      for (int r = 0; r < 4; ++r) {
        float v = acc[i][j][r] + bz;
        if (OBF) Cb[(size_t)(rr + r) * N + cc] = f2bf(v);
        else     Cf[(size_t)(rr + r) * N + cc] = v;
      }
    }
  }
}

// ---------------------------------------------------------------------------
// kv + ksum with MFMA. grid (64 bh, NSPLIT). Per 64-row L chunk:
//  projT[m][l] = (orf_hi+orf_lo)·(k_hi+k_lo)  (3-term split MFMA)
//  phi = exp(projT - |k|^2/16) + eps  ->  KphiT bf16
//  kv[m][d]  += KphiT · V   (MFMA, B operand from transposed V tile)
// ---------------------------------------------------------------------------
__global__ __launch_bounds__(256) void kv_mfma(
    const float* __restrict__ kbuf, const unsigned short* __restrict__ vbuf,
    const unsigned short* __restrict__ orfhi, const unsigned short* __restrict__ orflo,
    float* __restrict__ pkv, float* __restrict__ pksum) {
  __shared__ __align__(16) unsigned short KsHi[64 * 64], KsLo[64 * 64], VT[64 * 64];
  __shared__ __align__(16) unsigned short OHi[64 * 64], OLo[64 * 64], KphiT[64 * 64];
  __shared__ float norms[64];
  const int tid = threadIdx.x, lane = tid & 63, w = tid >> 6;
  const int g = lane >> 4, li = lane & 15;
  const int bh = blockIdx.x, sp = blockIdx.y;
  const int b = bh >> 4, h = bh & 15;

  f32x4 kvacc[4][4] = {};   // [pass p][d frag]
  float ksacc[4][4] = {};   // [pass p][reg]

  const float* kb = kbuf + ((size_t)b * LL + (size_t)sp * LCH) * DD + h * DK;
  const unsigned short* vb = vbuf + ((size_t)b * LL + (size_t)sp * LCH) * DD + h * DK;

  for (int c = 0; c < LCH / 64; ++c) {
    {  // stage K hi/lo + norms (fp32 source)
      const int l = tid >> 2, d0 = (tid & 3) << 4;
      const float* src = kb + (size_t)(c * 64 + l) * DD + d0;
      float na = 0.f;
#pragma unroll
      for (int q = 0; q < 4; ++q) {
        float4 v = *(const float4*)(src + q * 4);
        na += v.x * v.x + v.y * v.y + v.z * v.z + v.w * v.w;
        ushort4 hi4, lo4;
        hi4.x = f2bf(v.x); lo4.x = f2bf(v.x - bf2f(hi4.x));
        hi4.y = f2bf(v.y); lo4.y = f2bf(v.y - bf2f(hi4.y));
        hi4.z = f2bf(v.z); lo4.z = f2bf(v.z - bf2f(hi4.z));
        hi4.w = f2bf(v.w); lo4.w = f2bf(v.w - bf2f(hi4.w));
        *(ushort4*)&KsHi[l * 64 + d0 + q * 4] = hi4;
        *(ushort4*)&KsLo[l * 64 + d0 + q * 4] = lo4;
      }
      na += __shfl_xor(na, 1);
      na += __shfl_xor(na, 2);
      if ((tid & 3) == 0) norms[l] = na * 0.0625f;   // 1/(2*sqrt(dk))
    }
    {  // stage V transposed: VT[d][l]
      const int l = tid & 63, dg = tid >> 6;
      const unsigned short* src = vb + (size_t)(c * 64 + l) * DD + dg * 16;
#pragma unroll
      for (int q = 0; q < 4; ++q) {
        ushort4 v = *(const ushort4*)(src + q * 4);
        VT[(dg * 16 + q * 4 + 0) * 64 + l] = v.x;
        VT[(dg * 16 + q * 4 + 1) * 64 + l] = v.y;
        VT[(dg * 16 + q * 4 + 2) * 64 + l] = v.z;
        VT[(dg * 16 + q * 4 + 3) * 64 + l] = v.w;
      }
    }
    __syncthreads();

#pragma unroll
    for (int p = 0; p < 4; ++p) {
      {  // stage orf pass tile [64 m][64 d] hi/lo
        const int m = tid >> 2, d0 = (tid & 3) << 4;
        *(bf16x8*)&OHi[m * 64 + d0]     = *(const bf16x8*)&orfhi[(p * 64 + m) * DK + d0];
        *(bf16x8*)&OHi[m * 64 + d0 + 8] = *(const bf16x8*)&orfhi[(p * 64 + m) * DK + d0 + 8];
        *(bf16x8*)&OLo[m * 64 + d0]     = *(const bf16x8*)&orflo[(p * 64 + m) * DK + d0];
        *(bf16x8*)&OLo[m * 64 + d0 + 8] = *(const bf16x8*)&orflo[(p * 64 + m) * DK + d0 + 8];
      }
      __syncthreads();
      // projT: A = orf rows (m), B = Ks rows (l cols); split 3x
      f32x4 pr[4] = {};
#pragma unroll
      for (int kk = 0; kk < 2; ++kk) {
        const bf16x8 ah = *(const bf16x8*)&OHi[(w * 16 + li) * 64 + kk * 32 + g * 8];
        const bf16x8 al = *(const bf16x8*)&OLo[(w * 16 + li) * 64 + kk * 32 + g * 8];
#pragma unroll
        for (int lf = 0; lf < 4; ++lf) {
          const bf16x8 bh = *(const bf16x8*)&KsHi[(lf * 16 + li) * 64 + kk * 32 + g * 8];
          const bf16x8 bl = *(const bf16x8*)&KsLo[(lf * 16 + li) * 64 + kk * 32 + g * 8];
          pr[lf] = mfma16(ah, bh, pr[lf]);
          pr[lf] = mfma16(ah, bl, pr[lf]);
          pr[lf] = mfma16(al, bh, pr[lf]);
        }
      }
      // phi + ksum + KphiT[m][l] write
#pragma unroll
      for (int lf = 0; lf < 4; ++lf) {
        const float nrm = norms[lf * 16 + li];
#pragma unroll
        for (int r = 0; r < 4; ++r) {
          float phi = __expf(pr[lf][r] - nrm) + EPSF;
          ksacc[p][r] += phi;
          KphiT[(w * 16 + 4 * g + r) * 64 + lf * 16 + li] = f2bf(phi);
        }
      }
      __syncthreads();
      // kv: A = KphiT rows (m), B cols d from VT rows
#pragma unroll
      for (int kk = 0; kk < 2; ++kk) {
        const bf16x8 a = *(const bf16x8*)&KphiT[(w * 16 + li) * 64 + kk * 32 + g * 8];
#pragma unroll
        for (int df = 0; df < 4; ++df) {
          const bf16x8 bv = *(const bf16x8*)&VT[(df * 16 + li) * 64 + kk * 32 + g * 8];
          kvacc[p][df] = mfma16(a, bv, kvacc[p][df]);
        }
      }
      __syncthreads();
    }
  }
  float* kvo = pkv + ((size_t)sp * 64 + bh) * (MMF * DK);
#pragma unroll
  for (int p = 0; p < 4; ++p)
#pragma unroll
    for (int df = 0; df < 4; ++df)
#pragma unroll
      for (int r = 0; r < 4; ++r)
        kvo[(p * 64 + w * 16 + 4 * g + r) * DK + df * 16 + li] = kvacc[p][df][r];

  float* kso = pksum + ((size_t)sp * 64 + bh) * MMF;
#pragma unroll
  for (int p = 0; p < 4; ++p)
#pragma unroll
    for (int r = 0; r < 4; ++r) {
      float s = ksacc[p][r];
      s += __shfl_xor(s, 1); s += __shfl_xor(s, 2);
      s += __shfl_xor(s, 4); s += __shfl_xor(s, 8);
      if (li == 0) kso[p * 64 + w * 16 + 4 * g + r] = s;
    }
}

// ---------------------------------------------------------------------------
// reduce partial kv/ksum over NSPLIT
// ---------------------------------------------------------------------------
__global__ __launch_bounds__(256) void reduce_parts(
    const float* __restrict__ pkv, float* __restrict__ kvg,
    const float* __restrict__ pks, float* __restrict__ ksg) {
  const int NKV4 = 64 * MMF * DK / 4;   // 262144
  const int NKS4 = 64 * MMF / 4;        // 4096
  int i = blockIdx.x * 256 + threadIdx.x;
  if (i < NKV4) {
    float4 s = {0.f, 0.f, 0.f, 0.f};
#pragma unroll
    for (int sp = 0; sp < NSPLIT; ++sp) {
      float4 v = *(const float4*)&pkv[((size_t)sp * NKV4 + i) * 4];
      s.x += v.x; s.y += v.y; s.z += v.z; s.w += v.w;
    }
    *(float4*)&kvg[(size_t)i * 4] = s;
  }
  if (i < NKS4) {
    float4 s = {0.f, 0.f, 0.f, 0.f};
#pragma unroll
    for (int sp = 0; sp < NSPLIT; ++sp) {
      float4 v = *(const float4*)&pks[((size_t)sp * NKS4 + i) * 4];
      s.x += v.x; s.y += v.y; s.z += v.z; s.w += v.w;
    }
    *(float4*)&ksg[(size_t)i * 4] = s;
  }
}

// ---------------------------------------------------------------------------
// q_phi + num/den -> attn (bf16). grid (64 bh, 64 l-blocks).
// ---------------------------------------------------------------------------
__global__ __launch_bounds__(256) void qattn_mfma(
    const float* __restrict__ qbuf,
    const unsigned short* __restrict__ orfhi, const unsigned short* __restrict__ orflo,
    const float* __restrict__ kvg, const float* __restrict__ ksg,
    unsigned short* __restrict__ attn) {
  __shared__ __align__(16) unsigned short QsHi[64 * 64], QsLo[64 * 64];
  __shared__ __align__(16) unsigned short OHi[64 * 64], OLo[64 * 64];
  __shared__ __align__(16) unsigned short KvT[64 * 64];
  __shared__ __align__(16) unsigned short Qphi[4][16 * 64];
  __shared__ float ksums[64];
  __shared__ float norms[64];
  const int tid = threadIdx.x, lane = tid & 63, w = tid >> 6;
  const int g = lane >> 4, li = lane & 15;
  const int bh = blockIdx.x, lb = blockIdx.y;
  const int b = bh >> 4, h = bh & 15;
  const float* qb = qbuf + ((size_t)b * LL + (size_t)lb * 64) * DD + h * DK;

  {  // stage Q hi/lo + norms
    const int l = tid >> 2, d0 = (tid & 3) << 4;
    const float* src = qb + (size_t)l * DD + d0;
    float na = 0.f;
#pragma unroll
    for (int q = 0; q < 4; ++q) {
      float4 v = *(const float4*)(src + q * 4);
      na += v.x * v.x + v.y * v.y + v.z * v.z + v.w * v.w;
      ushort4 hi4, lo4;
      hi4.x = f2bf(v.x); lo4.x = f2bf(v.x - bf2f(hi4.x));
      hi4.y = f2bf(v.y); lo4.y = f2bf(v.y - bf2f(hi4.y));
      hi4.z = f2bf(v.z); lo4.z = f2bf(v.z - bf2f(hi4.z));
      hi4.w = f2bf(v.w); lo4.w = f2bf(v.w - bf2f(hi4.w));
      *(ushort4*)&QsHi[l * 64 + d0 + q * 4] = hi4;
      *(ushort4*)&QsLo[l * 64 + d0 + q * 4] = lo4;
    }
    na += __shfl_xor(na, 1);
    na += __shfl_xor(na, 2);
    if ((tid & 3) == 0) norms[l] = na * 0.0625f;
  }

  f32x4 numacc[4] = {};
  float denacc[4] = {};

#pragma unroll
  for (int p = 0; p < 4; ++p) {
    __syncthreads();   // p=0: publishes Qs/norms; p>0: protects OHi/KvT/ksums
    {  // stage orf pass tile
      const int m = tid >> 2, d0 = (tid & 3) << 4;
      *(bf16x8*)&OHi[m * 64 + d0]     = *(const bf16x8*)&orfhi[(p * 64 + m) * DK + d0];
      *(bf16x8*)&OHi[m * 64 + d0 + 8] = *(const bf16x8*)&orfhi[(p * 64 + m) * DK + d0 + 8];
      *(bf16x8*)&OLo[m * 64 + d0]     = *(const bf16x8*)&orflo[(p * 64 + m) * DK + d0];
      *(bf16x8*)&OLo[m * 64 + d0 + 8] = *(const bf16x8*)&orflo[(p * 64 + m) * DK + d0 + 8];
    }
    {  // stage kv transposed: KvT[d][m-local]
      const int mm = tid & 63, dg = tid >> 6;
      const float* kvsrc = kvg + ((size_t)bh * MMF + p * 64 + mm) * DK + dg * 16;
#pragma unroll
      for (int q = 0; q < 4; ++q) {
        float4 v = *(const float4*)(kvsrc + q * 4);
        KvT[(dg * 16 + q * 4 + 0) * 64 + mm] = f2bf(v.x);
        KvT[(dg * 16 + q * 4 + 1) * 64 + mm] = f2bf(v.y);
        KvT[(dg * 16 + q * 4 + 2) * 64 + mm] = f2bf(v.z);
        KvT[(dg * 16 + q * 4 + 3) * 64 + mm] = f2bf(v.w);
      }
    }
    if (tid < 64) ksums[tid] = ksg[(size_t)bh * MMF + p * 64 + tid];
    __syncthreads();

    // proj[l][m]: A = Qs rows (l), B = orf rows (m cols); split 3x
    f32x4 pr[4] = {};
#pragma unroll
    for (int kk = 0; kk < 2; ++kk) {
      const bf16x8 ah = *(const bf16x8*)&QsHi[(w * 16 + li) * 64 + kk * 32 + g * 8];
      const bf16x8 al = *(const bf16x8*)&QsLo[(w * 16 + li) * 64 + kk * 32 + g * 8];
#pragma unroll
      for (int mf = 0; mf < 4; ++mf) {
        const bf16x8 bh = *(const bf16x8*)&OHi[(mf * 16 + li) * 64 + kk * 32 + g * 8];
        const bf16x8 bl = *(const bf16x8*)&OLo[(mf * 16 + li) * 64 + kk * 32 + g * 8];
        pr[mf] = mfma16(ah, bh, pr[mf]);
        pr[mf] = mfma16(ah, bl, pr[mf]);
        pr[mf] = mfma16(al, bh, pr[mf]);
      }
    }
    // phi, den partial, Qphi[l-local][m-local] write (wave-private region)
#pragma unroll
    for (int mf = 0; mf < 4; ++mf) {
      const float ks = ksums[mf * 16 + li];
#pragma unroll
      for (int r = 0; r < 4; ++r) {
        float phi = __expf(pr[mf][r] - norms[w * 16 + 4 * g + r]) + EPSF;
        denacc[r] += phi * ks;
        Qphi[w][(4 * g + r) * 64 + mf * 16 + li] = f2bf(phi);
      }
    }
    // num += Qphi · KvT  (same-wave LDS dependence; compiler inserts waits)
#pragma unroll
    for (int kk = 0; kk < 2; ++kk) {
      const bf16x8 a = *(const bf16x8*)&Qphi[w][li * 64 + kk * 32 + g * 8];
#pragma unroll
      for (int df = 0; df < 4; ++df) {
        const bf16x8 bv = *(const bf16x8*)&KvT[(df * 16 + li) * 64 + kk * 32 + g * 8];
        numacc[df] = mfma16(a, bv, numacc[df]);
      }
    }
  }
  float den[4];
#pragma unroll
  for (int r = 0; r < 4; ++r) {
    float s = denacc[r];
    s += __shfl_xor(s, 1); s += __shfl_xor(s, 2);
    s += __shfl_xor(s, 4); s += __shfl_xor(s, 8);
    den[r] = s;
  }
  unsigned short* ab = attn + ((size_t)b * LL + (size_t)lb * 64) * DD + h * DK;
#pragma unroll
  for (int df = 0; df < 4; ++df)
#pragma unroll
    for (int r = 0; r < 4; ++r)
      ab[(size_t)(w * 16 + 4 * g + r) * DD + df * 16 + li] =
          f2bf(numacc[df][r] / den[r]);
}

// ---------------------------------------------------------------------------
extern "C" void kernel_launch(void* const* d_in, const int* in_sizes, int n_in,
                              void* d_out, int out_size, void* d_ws, size_t ws_size,
                              hipStream_t stream) {
  (void)in_sizes; (void)n_in; (void)out_size; (void)ws_size;
  const float* x   = (const float*)d_in[0];
  const float* Wq  = (const float*)d_in[1];
  const float* bq  = (const float*)d_in[2];
  const float* Wk  = (const float*)d_in[3];
  const float* bk  = (const float*)d_in[4];
  const float* Wv  = (const float*)d_in[5];
  const float* bv  = (const float*)d_in[6];
  const float* Wo  = (const float*)d_in[7];
  const float* bo  = (const float*)d_in[8];
  const float* orf = (const float*)d_in[9];
  float* out = (float*)d_out;

  const size_t ND = (size_t)BB * LL * DD;   // 16,777,216
  char* base = (char*)d_ws;
  size_t off = 0;
  auto alloc = [&](size_t bytes) -> char* {
    char* p = base + off;
    off += (bytes + 255) & ~(size_t)255;
    return p;
  };
  unsigned short* wqbf  = (unsigned short*)alloc((size_t)DD * DD * 2);
  unsigned short* wkbf  = (unsigned short*)alloc((size_t)DD * DD * 2);
  unsigned short* wvbf  = (unsigned short*)alloc((size_t)DD * DD * 2);
  unsigned short* wobf  = (unsigned short*)alloc((size_t)DD * DD * 2);
  unsigned short* orfhi = (unsigned short*)alloc((size_t)MMF * DK * 2);
  unsigned short* orflo = (unsigned short*)alloc((size_t)MMF * DK * 2);
  unsigned short* xbf   = (unsigned short*)alloc(ND * 2);          // -> pkv later
  float*          pksum = (float*)alloc((size_t)NSPLIT * 64 * MMF * 4);
  float*          qbuf  = (float*)alloc(ND * 4);
  float*          kbuf  = (float*)alloc(ND * 4);                   // -> attnbf later
  unsigned short* vbf   = (unsigned short*)alloc(ND * 2);
  float*          kvg   = (float*)alloc((size_t)64 * MMF * DK * 4);
  float*          ksg   = (float*)alloc((size_t)64 * MMF * 4);
  float*          pkv   = (float*)xbf;           // 33.55 MB, exact alias
  unsigned short* attnbf = (unsigned short*)kbuf;

  cvt_bf16<<<16384, 256, 0, stream>>>(x, xbf, (int)ND);
  cvt_bf16<<<1024, 256, 0, stream>>>(Wq, wqbf, DD * DD);
  cvt_bf16<<<1024, 256, 0, stream>>>(Wk, wkbf, DD * DD);
  cvt_bf16<<<1024, 256, 0, stream>>>(Wv, wvbf, DD * DD);
  cvt_bf16<<<1024, 256, 0, stream>>>(Wo, wobf, DD * DD);
  cvt_orf<<<64, 256, 0, stream>>>(orf, orfhi, orflo, MMF * DK);

  dim3 gg(128, 8);
  gemm_mfma<0><<<gg, 256, 0, stream>>>(xbf, wqbf, bq, qbuf, (unsigned short*)0,
                                       BB * LL, DD, DD);
  gemm_mfma<0><<<gg, 256, 0, stream>>>(xbf, wkbf, bk, kbuf, (unsigned short*)0,
                                       BB * LL, DD, DD);
  gemm_mfma<1><<<gg, 256, 0, stream>>>(xbf, wvbf, bv, (float*)0, vbf,
                                       BB * LL, DD, DD);

  kv_mfma<<<dim3(64, NSPLIT), 256, 0, stream>>>(kbuf, vbf, orfhi, orflo, pkv, pksum);
  reduce_parts<<<1024, 256, 0, stream>>>(pkv, kvg, pksum, ksg);
  qattn_mfma<<<dim3(64, 64), 256, 0, stream>>>(qbuf, orfhi, orflo, kvg, ksg, attnbf);

  gemm_mfma<0><<<gg, 256, 0, stream>>>(attnbf, wobf, bo, out, (unsigned short*)0,
                                       BB * LL, DD, DD);
}

// Round 3
// 388.365 us; speedup vs baseline: 6.1904x; 1.1640x over previous
//
#include <hip/hip_runtime.h>
#include <math.h>

// Problem constants
#define HH 16
#define BB 4
#define LL 4096
#define DD 1024
#define DK 64
#define MMF 256
#define EPSF 1e-6f
#define DK4INV 0.35355339059327373f   // 64^-0.25, folded into orf
#define NSPLIT 8
#define LCH (LL / NSPLIT)             // 512 rows of L per kv block

typedef __attribute__((ext_vector_type(8))) short bf16x8;
typedef __attribute__((ext_vector_type(4))) float f32x4;

__device__ __forceinline__ unsigned short f2bf(float f) {
  union { float f; unsigned u; } v; v.f = f;
  unsigned r = v.u + 0x7FFF + ((v.u >> 16) & 1);   // RNE
  return (unsigned short)(r >> 16);
}
__device__ __forceinline__ float bf2f(unsigned short h) {
  union { unsigned u; float f; } v; v.u = ((unsigned)h) << 16;
  return v.f;
}
__device__ __forceinline__ f32x4 mfma16(bf16x8 a, bf16x8 b, f32x4 c) {
  return __builtin_amdgcn_mfma_f32_16x16x32_bf16(a, b, c, 0, 0, 0);
}
// async global->LDS, 16B per lane; dst must be wave-uniform (lane x16 implicit)
__device__ __forceinline__ void gload16(const unsigned short* g, unsigned short* l) {
  __builtin_amdgcn_global_load_lds(
      (const __attribute__((address_space(1))) void*)g,
      (__attribute__((address_space(3))) void*)l, 16, 0, 0);
}
// T2 swizzle for 64-element rows (element-index xor)
#define SWZ(row, col) ((col) ^ (((row) & 7) << 3))

// ---------------------------------------------------------------------------
// fp32 -> bf16 conversion (n multiple of 4)
// ---------------------------------------------------------------------------
__global__ __launch_bounds__(256) void cvt_bf16(
    const float* __restrict__ src, unsigned short* __restrict__ dst, int n) {
  int i = (blockIdx.x * 256 + threadIdx.x) * 4;
  if (i < n) {
    float4 v = *(const float4*)&src[i];
    ushort4 o;
    o.x = f2bf(v.x); o.y = f2bf(v.y); o.z = f2bf(v.z); o.w = f2bf(v.w);
    *(ushort4*)&dst[i] = o;
  }
}

// orf: scale by DK4INV, split hi/lo bf16
__global__ __launch_bounds__(256) void cvt_orf(
    const float* __restrict__ src, unsigned short* __restrict__ hi,
    unsigned short* __restrict__ lo, int n) {
  int i = blockIdx.x * 256 + threadIdx.x;
  if (i < n) {
    float f = src[i] * DK4INV;
    unsigned short h = f2bf(f);
    hi[i] = h;
    lo[i] = f2bf(f - bf2f(h));
  }
}

// ---------------------------------------------------------------------------
// bf16 MFMA GEMM: C[M,N] = A[M,K] @ W[N,K]^T + bias. 128x128 tile, BK=64,
// 4 waves (2x2). Staging via global_load_lds(16B) with pre-swizzled source;
// fragment reads XOR-swizzled (conflict-free).
// OBF=0: fp32 C [M,N].  OBF=1: bf16 TRANSPOSED store Ct[(b*16+h)*64+d][4096].
// ---------------------------------------------------------------------------
template <int OBF>
__global__ __launch_bounds__(256) void gemm_mfma(
    const unsigned short* __restrict__ A, const unsigned short* __restrict__ W,
    const float* __restrict__ bias, float* __restrict__ Cf,
    unsigned short* __restrict__ Cb, int M, int N, int K) {
  __shared__ __align__(16) unsigned short As[128 * 64];
  __shared__ __align__(16) unsigned short Bs[128 * 64];
  const int tid = threadIdx.x, lane = tid & 63;
  const int w = tid >> 6, wr = w >> 1, wc = w & 1;
  const int g = lane >> 4, li = lane & 15;
  const int m0 = blockIdx.x * 128, n0 = blockIdx.y * 128;

  f32x4 acc[4][4] = {};
  const int srow8 = lane >> 3;                    // row within 8-row group
  const int scol  = ((lane & 7) ^ srow8) << 3;    // pre-swizzled element col
  const unsigned short* Ag = A + (size_t)(m0 + w * 32 + srow8) * K + scol;
  const unsigned short* Wg = W + (size_t)(n0 + w * 32 + srow8) * K + scol;

  for (int k0 = 0; k0 < K; k0 += 64) {
    __syncthreads();
#pragma unroll
    for (int j = 0; j < 4; ++j) {
      gload16(Ag + (size_t)j * 8 * K + k0, &As[(w * 32 + j * 8) * 64]);
      gload16(Wg + (size_t)j * 8 * K + k0, &Bs[(w * 32 + j * 8) * 64]);
    }
    __syncthreads();
    const int sx = (li & 7) << 3;
#pragma unroll
    for (int kk = 0; kk < 2; ++kk) {
      const int c = (kk * 32 + g * 8) ^ sx;
      bf16x8 af[4], bfr[4];
#pragma unroll
      for (int i = 0; i < 4; ++i)
        af[i] = *(const bf16x8*)&As[(wr * 64 + i * 16 + li) * 64 + c];
#pragma unroll
      for (int j = 0; j < 4; ++j)
        bfr[j] = *(const bf16x8*)&Bs[(wc * 64 + j * 16 + li) * 64 + c];
#pragma unroll
      for (int i = 0; i < 4; ++i)
#pragma unroll
        for (int j = 0; j < 4; ++j)
          acc[i][j] = mfma16(af[i], bfr[j], acc[i][j]);
    }
  }
#pragma unroll
  for (int i = 0; i < 4; ++i) {
    const int rr = m0 + wr * 64 + i * 16 + 4 * g;
#pragma unroll
    for (int j = 0; j < 4; ++j) {
      const int cc = n0 + wc * 64 + j * 16 + li;
      const float bz = bias[cc];
      if (OBF) {
        // transposed bf16: row = b*1024 + cc (head-dim), col = l
        const int b = rr >> 12, l = rr & 4095;
        ushort4 o;
        o.x = f2bf(acc[i][j][0] + bz); o.y = f2bf(acc[i][j][1] + bz);
        o.z = f2bf(acc[i][j][2] + bz); o.w = f2bf(acc[i][j][3] + bz);
        *(ushort4*)&Cb[((size_t)b * 1024 + cc) * 4096 + l] = o;
      } else {
#pragma unroll
        for (int r = 0; r < 4; ++r)
          Cf[(size_t)(rr + r) * N + cc] = acc[i][j][r] + bz;
      }
    }
  }
}

// ---------------------------------------------------------------------------
// kv + ksum with MFMA. grid (64 bh, NSPLIT).
//  K tiles: fp32 load -> hi/lo bf16 split (VALU), swizzled ds_writes.
//  Vt / orf tiles: global_load_lds with pre-swizzled source.
// ---------------------------------------------------------------------------
__global__ __launch_bounds__(256) void kv_mfma(
    const float* __restrict__ kbuf, const unsigned short* __restrict__ vt,
    const unsigned short* __restrict__ orfhi, const unsigned short* __restrict__ orflo,
    float* __restrict__ pkv, float* __restrict__ pksum) {
  __shared__ __align__(16) unsigned short KsHi[64 * 64], KsLo[64 * 64], VT[64 * 64];
  __shared__ __align__(16) unsigned short OHi[64 * 64], OLo[64 * 64], KphiT[64 * 64];
  __shared__ float norms[64];
  const int tid = threadIdx.x, lane = tid & 63, w = tid >> 6;
  const int g = lane >> 4, li = lane & 15;
  const int bh = blockIdx.x, sp = blockIdx.y;
  const int b = bh >> 4, h = bh & 15;

  f32x4 kvacc[4][4] = {};
  float ksacc[4][4] = {};

  const float* kb = kbuf + ((size_t)b * LL + (size_t)sp * LCH) * DD + h * DK;
  const int srow8 = lane >> 3;
  const int scol  = ((lane & 7) ^ srow8) << 3;
  const unsigned short* vtg = vt + ((size_t)bh * 64 + w * 16 + srow8) * LL + scol;
  const int sx = (li & 7) << 3;

  for (int c = 0; c < LCH / 64; ++c) {
    const int l0 = sp * LCH + c * 64;
    __syncthreads();   // prior chunk/pass readers done
    // V^T tile rows w*16..w*16+15 (pre-swizzled source, linear LDS)
    gload16(vtg + l0, &VT[(w * 16) * 64]);
    gload16(vtg + (size_t)8 * LL + l0, &VT[(w * 16 + 8) * 64]);
    {  // stage K hi/lo (swizzled writes) + norms
      const int l = tid >> 2, d0 = (tid & 3) << 4;
      const float* src = kb + (size_t)(c * 64 + l) * DD + d0;
      float na = 0.f;
#pragma unroll
      for (int q = 0; q < 4; ++q) {
        float4 v = *(const float4*)(src + q * 4);
        na += v.x * v.x + v.y * v.y + v.z * v.z + v.w * v.w;
        ushort4 hi4, lo4;
        hi4.x = f2bf(v.x); lo4.x = f2bf(v.x - bf2f(hi4.x));
        hi4.y = f2bf(v.y); lo4.y = f2bf(v.y - bf2f(hi4.y));
        hi4.z = f2bf(v.z); lo4.z = f2bf(v.z - bf2f(hi4.z));
        hi4.w = f2bf(v.w); lo4.w = f2bf(v.w - bf2f(hi4.w));
        const int e = l * 64 + SWZ(l, d0 + q * 4);
        *(ushort4*)&KsHi[e] = hi4;
        *(ushort4*)&KsLo[e] = lo4;
      }
      na += __shfl_xor(na, 1);
      na += __shfl_xor(na, 2);
      if ((tid & 3) == 0) norms[l] = na * 0.0625f;   // 1/(2*sqrt(dk))
    }
    __syncthreads();

#pragma unroll
    for (int p = 0; p < 4; ++p) {
      if (p) __syncthreads();   // prior pass's OHi/OLo readers done
      {  // orf pass tile via gload (pre-swizzled source)
        const size_t ro = (size_t)(p * 64 + w * 16 + srow8) * 64 + scol;
        gload16(orfhi + ro, &OHi[(w * 16) * 64]);
        gload16(orfhi + ro + 8 * 64, &OHi[(w * 16 + 8) * 64]);
        gload16(orflo + ro, &OLo[(w * 16) * 64]);
        gload16(orflo + ro + 8 * 64, &OLo[(w * 16 + 8) * 64]);
      }
      __syncthreads();
      // projT[m][l]: A = orf rows (m), B = Ks rows (l); 3-term split
      f32x4 pr[4] = {};
#pragma unroll
      for (int kk = 0; kk < 2; ++kk) {
        const int cx = (kk * 32 + g * 8) ^ sx;
        const bf16x8 ah = *(const bf16x8*)&OHi[(w * 16 + li) * 64 + cx];
        const bf16x8 al = *(const bf16x8*)&OLo[(w * 16 + li) * 64 + cx];
#pragma unroll
        for (int lf = 0; lf < 4; ++lf) {
          const bf16x8 bh2 = *(const bf16x8*)&KsHi[(lf * 16 + li) * 64 + cx];
          const bf16x8 bl2 = *(const bf16x8*)&KsLo[(lf * 16 + li) * 64 + cx];
          pr[lf] = mfma16(ah, bh2, pr[lf]);
          pr[lf] = mfma16(ah, bl2, pr[lf]);
          pr[lf] = mfma16(al, bh2, pr[lf]);
        }
      }
      // phi + ksum + KphiT (wave-private rows, swizzled)
#pragma unroll
      for (int lf = 0; lf < 4; ++lf) {
        const float nrm = norms[lf * 16 + li];
#pragma unroll
        for (int r = 0; r < 4; ++r) {
          float phi = __expf(pr[lf][r] - nrm) + EPSF;
          ksacc[p][r] += phi;
          const int row = w * 16 + 4 * g + r;
          KphiT[row * 64 + SWZ(row, lf * 16 + li)] = f2bf(phi);
        }
      }
      // kv: A = KphiT rows (m, same-wave), B = VT rows (d)
#pragma unroll
      for (int kk = 0; kk < 2; ++kk) {
        const int cx = (kk * 32 + g * 8) ^ sx;
        const bf16x8 a = *(const bf16x8*)&KphiT[(w * 16 + li) * 64 + cx];
#pragma unroll
        for (int df = 0; df < 4; ++df) {
          const bf16x8 bv = *(const bf16x8*)&VT[(df * 16 + li) * 64 + cx];
          kvacc[p][df] = mfma16(a, bv, kvacc[p][df]);
        }
      }
    }
  }
  float* kvo = pkv + ((size_t)sp * 64 + bh) * (MMF * DK);
#pragma unroll
  for (int p = 0; p < 4; ++p)
#pragma unroll
    for (int df = 0; df < 4; ++df)
#pragma unroll
      for (int r = 0; r < 4; ++r)
        kvo[(p * 64 + w * 16 + 4 * g + r) * DK + df * 16 + li] = kvacc[p][df][r];

  float* kso = pksum + ((size_t)sp * 64 + bh) * MMF;
#pragma unroll
  for (int p = 0; p < 4; ++p)
#pragma unroll
    for (int r = 0; r < 4; ++r) {
      float s = ksacc[p][r];
      s += __shfl_xor(s, 1); s += __shfl_xor(s, 2);
      s += __shfl_xor(s, 4); s += __shfl_xor(s, 8);
      if (li == 0) kso[p * 64 + w * 16 + 4 * g + r] = s;
    }
}

// ---------------------------------------------------------------------------
// reduce partials; emit kv TRANSPOSED bf16 kvT[bh][d][m] + ksum fp32
// ---------------------------------------------------------------------------
__global__ __launch_bounds__(256) void reduce_parts(
    const float* __restrict__ pkv, unsigned short* __restrict__ kvT,
    const float* __restrict__ pks, float* __restrict__ ksg) {
  const int id = blockIdx.x * 256 + threadIdx.x;   // grid 1024 -> 262144
  {
    const int bh = id >> 12, rest = id & 4095;
    const int m0 = (rest >> 6) << 2, d = rest & 63;
    float s0 = 0.f, s1 = 0.f, s2 = 0.f, s3 = 0.f;
#pragma unroll
    for (int sp = 0; sp < NSPLIT; ++sp) {
      const float* p = pkv + (size_t)(sp * 64 + bh) * (MMF * DK) + d;
      s0 += p[(m0 + 0) * DK]; s1 += p[(m0 + 1) * DK];
      s2 += p[(m0 + 2) * DK]; s3 += p[(m0 + 3) * DK];
    }
    ushort4 o;
    o.x = f2bf(s0); o.y = f2bf(s1); o.z = f2bf(s2); o.w = f2bf(s3);
    *(ushort4*)&kvT[((size_t)bh * DK + d) * MMF + m0] = o;
  }
  if (id < 4096) {   // 64*256/4 float4s of ksum
    float4 s = {0.f, 0.f, 0.f, 0.f};
#pragma unroll
    for (int sp = 0; sp < NSPLIT; ++sp) {
      float4 v = *(const float4*)&pks[(size_t)sp * 64 * MMF + id * 4];
      s.x += v.x; s.y += v.y; s.z += v.z; s.w += v.w;
    }
    *(float4*)&ksg[id * 4] = s;
  }
}

// ---------------------------------------------------------------------------
// q_phi + num/den -> attn (bf16). grid (64 bh, 64 l-blocks).
// orf & kvT tiles staged via gload (pre-swizzled); Q hi/lo VALU-staged swizzled.
// ---------------------------------------------------------------------------
__global__ __launch_bounds__(256) void qattn_mfma(
    const float* __restrict__ qbuf,
    const unsigned short* __restrict__ orfhi, const unsigned short* __restrict__ orflo,
    const unsigned short* __restrict__ kvT, const float* __restrict__ ksg,
    unsigned short* __restrict__ attn) {
  __shared__ __align__(16) unsigned short QsHi[64 * 64], QsLo[64 * 64];
  __shared__ __align__(16) unsigned short OHi[64 * 64], OLo[64 * 64];
  __shared__ __align__(16) unsigned short KvTs[64 * 64];
  __shared__ __align__(16) unsigned short Qphi[4][16 * 64];
  __shared__ float ksums[64];
  __shared__ float norms[64];
  const int tid = threadIdx.x, lane = tid & 63, w = tid >> 6;
  const int g = lane >> 4, li = lane & 15;
  const int bh = blockIdx.x, lb = blockIdx.y;
  const int b = bh >> 4, h = bh & 15;
  const float* qb = qbuf + ((size_t)b * LL + (size_t)lb * 64) * DD + h * DK;
  const int srow8 = lane >> 3;
  const int scol  = ((lane & 7) ^ srow8) << 3;
  const int sx = (li & 7) << 3;

  {  // stage Q hi/lo (swizzled) + norms
    const int l = tid >> 2, d0 = (tid & 3) << 4;
    const float* src = qb + (size_t)l * DD + d0;
    float na = 0.f;
#pragma unroll
    for (int q = 0; q < 4; ++q) {
      float4 v = *(const float4*)(src + q * 4);
      na += v.x * v.x + v.y * v.y + v.z * v.z + v.w * v.w;
      ushort4 hi4, lo4;
      hi4.x = f2bf(v.x); lo4.x = f2bf(v.x - bf2f(hi4.x));
      hi4.y = f2bf(v.y); lo4.y = f2bf(v.y - bf2f(hi4.y));
      hi4.z = f2bf(v.z); lo4.z = f2bf(v.z - bf2f(hi4.z));
      hi4.w = f2bf(v.w); lo4.w = f2bf(v.w - bf2f(hi4.w));
      const int e = l * 64 + SWZ(l, d0 + q * 4);
      *(ushort4*)&QsHi[e] = hi4;
      *(ushort4*)&QsLo[e] = lo4;
    }
    na += __shfl_xor(na, 1);
    na += __shfl_xor(na, 2);
    if ((tid & 3) == 0) norms[l] = na * 0.0625f;
  }

  f32x4 numacc[4] = {};
  float denacc[4] = {};

#pragma unroll
  for (int p = 0; p < 4; ++p) {
    __syncthreads();   // p=0: Qs/norms ready; p>0: prior pass readers done
    {  // gload orf + kvT tiles (pre-swizzled sources)
      const size_t ro = (size_t)(p * 64 + w * 16 + srow8) * 64 + scol;
      gload16(orfhi + ro, &OHi[(w * 16) * 64]);
      gload16(orfhi + ro + 8 * 64, &OHi[(w * 16 + 8) * 64]);
      gload16(orflo + ro, &OLo[(w * 16) * 64]);
      gload16(orflo + ro + 8 * 64, &OLo[(w * 16 + 8) * 64]);
      const unsigned short* kq =
          kvT + ((size_t)bh * DK + w * 16 + srow8) * MMF + p * 64 + scol;
      gload16(kq, &KvTs[(w * 16) * 64]);
      gload16(kq + 8 * MMF, &KvTs[(w * 16 + 8) * 64]);
    }
    if (tid < 64) ksums[tid] = ksg[(size_t)bh * MMF + p * 64 + tid];
    __syncthreads();

    // proj[l][m]: A = Qs rows (l), B = orf rows (m); 3-term split
    f32x4 pr[4] = {};
#pragma unroll
    for (int kk = 0; kk < 2; ++kk) {
      const int cx = (kk * 32 + g * 8) ^ sx;
      const bf16x8 ah = *(const bf16x8*)&QsHi[(w * 16 + li) * 64 + cx];
      const bf16x8 al = *(const bf16x8*)&QsLo[(w * 16 + li) * 64 + cx];
#pragma unroll
      for (int mf = 0; mf < 4; ++mf) {
        const bf16x8 bh2 = *(const bf16x8*)&OHi[(mf * 16 + li) * 64 + cx];
        const bf16x8 bl2 = *(const bf16x8*)&OLo[(mf * 16 + li) * 64 + cx];
        pr[mf] = mfma16(ah, bh2, pr[mf]);
        pr[mf] = mfma16(ah, bl2, pr[mf]);
        pr[mf] = mfma16(al, bh2, pr[mf]);
      }
    }
    // phi, den partial, Qphi (wave-private, swizzled)
#pragma unroll
    for (int mf = 0; mf < 4; ++mf) {
      const float ks = ksums[mf * 16 + li];
#pragma unroll
      for (int r = 0; r < 4; ++r) {
        float phi = __expf(pr[mf][r] - norms[w * 16 + 4 * g + r]) + EPSF;
        denacc[r] += phi * ks;
        const int row = 4 * g + r;
        Qphi[w][row * 64 + SWZ(row, mf * 16 + li)] = f2bf(phi);
      }
    }
    // num += Qphi . KvTs (same-wave LDS dependence)
#pragma unroll
    for (int kk = 0; kk < 2; ++kk) {
      const int cx = (kk * 32 + g * 8) ^ sx;
      const bf16x8 a = *(const bf16x8*)&Qphi[w][li * 64 + cx];
#pragma unroll
      for (int df = 0; df < 4; ++df) {
        const bf16x8 bv = *(const bf16x8*)&KvTs[(df * 16 + li) * 64 + cx];
        numacc[df] = mfma16(a, bv, numacc[df]);
      }
    }
  }
  float den[4];
#pragma unroll
  for (int r = 0; r < 4; ++r) {
    float s = denacc[r];
    s += __shfl_xor(s, 1); s += __shfl_xor(s, 2);
    s += __shfl_xor(s, 4); s += __shfl_xor(s, 8);
    den[r] = s;
  }
  unsigned short* ab = attn + ((size_t)b * LL + (size_t)lb * 64) * DD + h * DK;
#pragma unroll
  for (int df = 0; df < 4; ++df)
#pragma unroll
    for (int r = 0; r < 4; ++r)
      ab[(size_t)(w * 16 + 4 * g + r) * DD + df * 16 + li] =
          f2bf(numacc[df][r] / den[r]);
}

// ---------------------------------------------------------------------------
extern "C" void kernel_launch(void* const* d_in, const int* in_sizes, int n_in,
                              void* d_out, int out_size, void* d_ws, size_t ws_size,
                              hipStream_t stream) {
  (void)in_sizes; (void)n_in; (void)out_size; (void)ws_size;
  const float* x   = (const float*)d_in[0];
  const float* Wq  = (const float*)d_in[1];
  const float* bq  = (const float*)d_in[2];
  const float* Wk  = (const float*)d_in[3];
  const float* bk  = (const float*)d_in[4];
  const float* Wv  = (const float*)d_in[5];
  const float* bv  = (const float*)d_in[6];
  const float* Wo  = (const float*)d_in[7];
  const float* bo  = (const float*)d_in[8];
  const float* orf = (const float*)d_in[9];
  float* out = (float*)d_out;

  const size_t ND = (size_t)BB * LL * DD;   // 16,777,216
  char* base = (char*)d_ws;
  size_t off = 0;
  auto alloc = [&](size_t bytes) -> char* {
    char* p = base + off;
    off += (bytes + 255) & ~(size_t)255;
    return p;
  };
  unsigned short* wqbf  = (unsigned short*)alloc((size_t)DD * DD * 2);
  unsigned short* wkbf  = (unsigned short*)alloc((size_t)DD * DD * 2);
  unsigned short* wvbf  = (unsigned short*)alloc((size_t)DD * DD * 2);
  unsigned short* wobf  = (unsigned short*)alloc((size_t)DD * DD * 2);
  unsigned short* orfhi = (unsigned short*)alloc((size_t)MMF * DK * 2);
  unsigned short* orflo = (unsigned short*)alloc((size_t)MMF * DK * 2);
  unsigned short* xbf   = (unsigned short*)alloc(ND * 2);          // -> pkv later
  float*          pksum = (float*)alloc((size_t)NSPLIT * 64 * MMF * 4);
  float*          qbuf  = (float*)alloc(ND * 4);
  float*          kbuf  = (float*)alloc(ND * 4);                   // -> attnbf later
  unsigned short* vtbuf = (unsigned short*)alloc(ND * 2);          // V transposed
  unsigned short* kvT   = (unsigned short*)alloc((size_t)64 * DK * MMF * 2);
  float*          ksg   = (float*)alloc((size_t)64 * MMF * 4);
  float*          pkv   = (float*)xbf;           // 33.55 MB, exact alias
  unsigned short* attnbf = (unsigned short*)kbuf;

  cvt_bf16<<<16384, 256, 0, stream>>>(x, xbf, (int)ND);
  cvt_bf16<<<1024, 256, 0, stream>>>(Wq, wqbf, DD * DD);
  cvt_bf16<<<1024, 256, 0, stream>>>(Wk, wkbf, DD * DD);
  cvt_bf16<<<1024, 256, 0, stream>>>(Wv, wvbf, DD * DD);
  cvt_bf16<<<1024, 256, 0, stream>>>(Wo, wobf, DD * DD);
  cvt_orf<<<64, 256, 0, stream>>>(orf, orfhi, orflo, MMF * DK);

  dim3 gg(128, 8);
  gemm_mfma<0><<<gg, 256, 0, stream>>>(xbf, wqbf, bq, qbuf, (unsigned short*)0,
                                       BB * LL, DD, DD);
  gemm_mfma<0><<<gg, 256, 0, stream>>>(xbf, wkbf, bk, kbuf, (unsigned short*)0,
                                       BB * LL, DD, DD);
  gemm_mfma<1><<<gg, 256, 0, stream>>>(xbf, wvbf, bv, (float*)0, vtbuf,
                                       BB * LL, DD, DD);

  kv_mfma<<<dim3(64, NSPLIT), 256, 0, stream>>>(kbuf, vtbuf, orfhi, orflo, pkv, pksum);
  reduce_parts<<<1024, 256, 0, stream>>>(pkv, kvT, pksum, ksg);
  qattn_mfma<<<dim3(64, 64), 256, 0, stream>>>(qbuf, orfhi, orflo, kvT, ksg, attnbf);

  gemm_mfma<0><<<gg, 256, 0, stream>>>(attnbf, wobf, bo, out, (unsigned short*)0,
                                       BB * LL, DD, DD);
}

// Round 4
// 364.582 us; speedup vs baseline: 6.5942x; 1.0652x over previous
//
#include <hip/hip_runtime.h>
#include <math.h>

// Problem constants
#define HH 16
#define BB 4
#define LL 4096
#define DD 1024
#define DK 64
#define MMF 256
#define EPSF 1e-6f
#define DK4INV 0.35355339059327373f   // 64^-0.25, folded into orf
#define NSPLIT 8
#define LCH (LL / NSPLIT)             // 512 rows of L per kv block

typedef __attribute__((ext_vector_type(8))) short bf16x8;
typedef __attribute__((ext_vector_type(4))) float f32x4;

__device__ __forceinline__ unsigned short f2bf(float f) {
  union { float f; unsigned u; } v; v.f = f;
  unsigned r = v.u + 0x7FFF + ((v.u >> 16) & 1);   // RNE
  return (unsigned short)(r >> 16);
}
__device__ __forceinline__ float bf2f(unsigned short h) {
  union { unsigned u; float f; } v; v.u = ((unsigned)h) << 16;
  return v.f;
}
__device__ __forceinline__ f32x4 mfma16(bf16x8 a, bf16x8 b, f32x4 c) {
  return __builtin_amdgcn_mfma_f32_16x16x32_bf16(a, b, c, 0, 0, 0);
}
// async global->LDS, 16B per lane; dst is wave-uniform base (lane x16 implicit)
__device__ __forceinline__ void gload16(const unsigned short* g, unsigned short* l) {
  __builtin_amdgcn_global_load_lds(
      (const __attribute__((address_space(1))) void*)g,
      (__attribute__((address_space(3))) void*)l, 16, 0, 0);
}
// T2 swizzle for 64-element bf16 rows (element-index xor)
#define SWZ(row, col) ((col) ^ (((row) & 7) << 3))

// ---------------------------------------------------------------------------
// fp32 -> bf16 conversion (n multiple of 4)
// ---------------------------------------------------------------------------
__global__ __launch_bounds__(256) void cvt_bf16(
    const float* __restrict__ src, unsigned short* __restrict__ dst, int n) {
  int i = (blockIdx.x * 256 + threadIdx.x) * 4;
  if (i < n) {
    float4 v = *(const float4*)&src[i];
    ushort4 o;
    o.x = f2bf(v.x); o.y = f2bf(v.y); o.z = f2bf(v.z); o.w = f2bf(v.w);
    *(ushort4*)&dst[i] = o;
  }
}

// orf: scale by DK4INV, split hi/lo bf16
__global__ __launch_bounds__(256) void cvt_orf(
    const float* __restrict__ src, unsigned short* __restrict__ hi,
    unsigned short* __restrict__ lo, int n) {
  int i = blockIdx.x * 256 + threadIdx.x;
  if (i < n) {
    float f = src[i] * DK4INV;
    unsigned short h = f2bf(f);
    hi[i] = h;
    lo[i] = f2bf(f - bf2f(h));
  }
}

// ---------------------------------------------------------------------------
// bf16 MFMA GEMM: C = A[M,K] @ W[N,K]^T + bias. 128x128 tile, BK=64, 4 waves.
// Fixed shape M=16384, N=1024 -> grid 128x8, XCD-swizzled.
// MODE 0: fp32 C row-major.
// MODE 1: bf16 transposed Ct[(b*16+h)*64+d][4096]           (V path)
// MODE 2: hi/lo bf16 [bh][l][64] + norms[bh][l] (pre /16)   (Q,K paths)
// ---------------------------------------------------------------------------
template <int MODE>
__global__ __launch_bounds__(256) void gemm_mfma(
    const unsigned short* __restrict__ A, const unsigned short* __restrict__ W,
    const float* __restrict__ bias, float* __restrict__ Cf,
    unsigned short* __restrict__ C1, unsigned short* __restrict__ C2,
    float* __restrict__ Cn, int M, int N, int K) {
  __shared__ __align__(16) unsigned short As[128 * 64];
  __shared__ __align__(16) unsigned short Bs[128 * 64];
  const int tid = threadIdx.x, lane = tid & 63;
  const int w = tid >> 6, wr = w >> 1, wc = w & 1;
  const int g = lane >> 4, li = lane & 15;
  // XCD swizzle: each XCD owns 16 contiguous M-panels x all 8 N-panels
  const int flat = blockIdx.y * gridDim.x + blockIdx.x;     // 0..1023
  const int xcd = flat & 7, loc = flat >> 3;
  const int m0 = ((xcd << 4) + (loc & 15)) * 128;
  const int n0 = (loc >> 4) * 128;

  f32x4 acc[4][4] = {};
  const int srow8 = lane >> 3;                    // row within 8-row group
  const int scol  = ((lane & 7) ^ srow8) << 3;    // pre-swizzled element col
  const unsigned short* Ag = A + (size_t)(m0 + w * 32 + srow8) * K + scol;
  const unsigned short* Wg = W + (size_t)(n0 + w * 32 + srow8) * K + scol;

  for (int k0 = 0; k0 < K; k0 += 64) {
    __syncthreads();
#pragma unroll
    for (int j = 0; j < 4; ++j) {
      gload16(Ag + (size_t)j * 8 * K + k0, &As[(w * 32 + j * 8) * 64]);
      gload16(Wg + (size_t)j * 8 * K + k0, &Bs[(w * 32 + j * 8) * 64]);
    }
    __syncthreads();
    const int sx = (li & 7) << 3;
#pragma unroll
    for (int kk = 0; kk < 2; ++kk) {
      const int c = (kk * 32 + g * 8) ^ sx;
      bf16x8 af[4], bfr[4];
#pragma unroll
      for (int i = 0; i < 4; ++i)
        af[i] = *(const bf16x8*)&As[(wr * 64 + i * 16 + li) * 64 + c];
#pragma unroll
      for (int j = 0; j < 4; ++j)
        bfr[j] = *(const bf16x8*)&Bs[(wc * 64 + j * 16 + li) * 64 + c];
#pragma unroll
      for (int i = 0; i < 4; ++i)
#pragma unroll
        for (int j = 0; j < 4; ++j)
          acc[i][j] = mfma16(af[i], bfr[j], acc[i][j]);
    }
  }

  if (MODE == 2) {
    const int head = (n0 + wc * 64) >> 6;
#pragma unroll
    for (int i = 0; i < 4; ++i) {
      const int rr = m0 + wr * 64 + i * 16 + 4 * g;
      const int b = rr >> 12, l = rr & 4095;
      const size_t rowb = (size_t)(b * 16 + head) * 4096 + l;
      float np[4] = {0.f, 0.f, 0.f, 0.f};
#pragma unroll
      for (int j = 0; j < 4; ++j) {
        const float bz = bias[n0 + wc * 64 + j * 16 + li];
        const int d = j * 16 + li;
#pragma unroll
        for (int r = 0; r < 4; ++r) {
          float v = acc[i][j][r] + bz;
          np[r] += v * v;
          unsigned short hv = f2bf(v);
          C1[(rowb + r) * 64 + d] = hv;
          C2[(rowb + r) * 64 + d] = f2bf(v - bf2f(hv));
        }
      }
#pragma unroll
      for (int r = 0; r < 4; ++r) {
        float s = np[r];
        s += __shfl_xor(s, 1); s += __shfl_xor(s, 2);
        s += __shfl_xor(s, 4); s += __shfl_xor(s, 8);
        if (li == 0) Cn[rowb + r] = s * 0.0625f;   // 1/(2*sqrt(dk))
      }
    }
  } else {
#pragma unroll
    for (int i = 0; i < 4; ++i) {
      const int rr = m0 + wr * 64 + i * 16 + 4 * g;
#pragma unroll
      for (int j = 0; j < 4; ++j) {
        const int cc = n0 + wc * 64 + j * 16 + li;
        const float bz = bias[cc];
        if (MODE == 1) {
          const int b = rr >> 12, l = rr & 4095;
          ushort4 o;
          o.x = f2bf(acc[i][j][0] + bz); o.y = f2bf(acc[i][j][1] + bz);
          o.z = f2bf(acc[i][j][2] + bz); o.w = f2bf(acc[i][j][3] + bz);
          *(ushort4*)&C1[((size_t)b * 1024 + cc) * 4096 + l] = o;
        } else {
#pragma unroll
          for (int r = 0; r < 4; ++r)
            Cf[(size_t)(rr + r) * N + cc] = acc[i][j][r] + bz;
        }
      }
    }
  }
}

// ---------------------------------------------------------------------------
// kv + ksum. grid (64 bh, NSPLIT). orf fragments in REGISTERS; K hi/lo, V^T
// staged via gload16 (pre-swizzled source); barrier-free 4-pass inner loop.
// ---------------------------------------------------------------------------
__global__ __launch_bounds__(256, 2) void kv_mfma(
    const unsigned short* __restrict__ khi, const unsigned short* __restrict__ klo,
    const float* __restrict__ knorms, const unsigned short* __restrict__ vt,
    const unsigned short* __restrict__ orfhi, const unsigned short* __restrict__ orflo,
    float* __restrict__ pkv, float* __restrict__ pksum) {
  __shared__ __align__(16) unsigned short KsHi[64 * 64], KsLo[64 * 64];
  __shared__ __align__(16) unsigned short VT[64 * 64], KphiT[64 * 64];
  __shared__ float ns[64];
  const int tid = threadIdx.x, lane = tid & 63, w = tid >> 6;
  const int g = lane >> 4, li = lane & 15;
  const int bh = blockIdx.x, sp = blockIdx.y;
  const int srow8 = lane >> 3;
  const int scol  = ((lane & 7) ^ srow8) << 3;
  const int sx = (li & 7) << 3;

  // orf fragments in registers: A-operand rows m = p*64 + w*16 + li
  bf16x8 oh[4][2], ol[4][2];
#pragma unroll
  for (int p = 0; p < 4; ++p)
#pragma unroll
    for (int kk = 0; kk < 2; ++kk) {
      const size_t o = (size_t)(p * 64 + w * 16 + li) * 64 + kk * 32 + g * 8;
      oh[p][kk] = *(const bf16x8*)&orfhi[o];
      ol[p][kk] = *(const bf16x8*)&orflo[o];
    }

  f32x4 kvacc[4][4] = {};
  float ksacc[4][4] = {};

  for (int c = 0; c < LCH / 64; ++c) {
    const int l0 = sp * LCH + c * 64;
    __syncthreads();   // previous chunk's readers done
    {  // stage K hi/lo + V^T via gload (pre-swizzled source, linear LDS)
      const size_t kb = ((size_t)bh * 4096 + l0 + w * 16 + srow8) * 64 + scol;
      gload16(khi + kb, &KsHi[(w * 16) * 64]);
      gload16(khi + kb + 8 * 64, &KsHi[(w * 16 + 8) * 64]);
      gload16(klo + kb, &KsLo[(w * 16) * 64]);
      gload16(klo + kb + 8 * 64, &KsLo[(w * 16 + 8) * 64]);
      const size_t vb = ((size_t)bh * 64 + w * 16 + srow8) * 4096 + l0 + scol;
      gload16(vt + vb, &VT[(w * 16) * 64]);
      gload16(vt + vb + (size_t)8 * 4096, &VT[(w * 16 + 8) * 64]);
      if (tid < 64) ns[tid] = knorms[(size_t)bh * 4096 + l0 + tid];
    }
    __syncthreads();

#pragma unroll
    for (int p = 0; p < 4; ++p) {
      // projT[m][l], 3-term hi/lo split
      f32x4 pr[4] = {};
#pragma unroll
      for (int kk = 0; kk < 2; ++kk) {
        const int cx = (kk * 32 + g * 8) ^ sx;
#pragma unroll
        for (int lf = 0; lf < 4; ++lf) {
          const bf16x8 bh2 = *(const bf16x8*)&KsHi[(lf * 16 + li) * 64 + cx];
          const bf16x8 bl2 = *(const bf16x8*)&KsLo[(lf * 16 + li) * 64 + cx];
          pr[lf] = mfma16(oh[p][kk], bh2, pr[lf]);
          pr[lf] = mfma16(oh[p][kk], bl2, pr[lf]);
          pr[lf] = mfma16(ol[p][kk], bh2, pr[lf]);
        }
      }
      // phi + ksum + KphiT (wave-private rows, swizzled)
#pragma unroll
      for (int lf = 0; lf < 4; ++lf) {
        const float nrm = ns[lf * 16 + li];
#pragma unroll
        for (int r = 0; r < 4; ++r) {
          float phi = __expf(pr[lf][r] - nrm) + EPSF;
          ksacc[p][r] += phi;
          const int row = w * 16 + 4 * g + r;
          KphiT[row * 64 + SWZ(row, lf * 16 + li)] = f2bf(phi);
        }
      }
      // kv += KphiT . V^T (same-wave LDS dependence, no barrier)
#pragma unroll
      for (int kk = 0; kk < 2; ++kk) {
        const int cx = (kk * 32 + g * 8) ^ sx;
        const bf16x8 a = *(const bf16x8*)&KphiT[(w * 16 + li) * 64 + cx];
#pragma unroll
        for (int df = 0; df < 4; ++df) {
          const bf16x8 bv = *(const bf16x8*)&VT[(df * 16 + li) * 64 + cx];
          kvacc[p][df] = mfma16(a, bv, kvacc[p][df]);
        }
      }
    }
  }
  float* kvo = pkv + ((size_t)sp * 64 + bh) * (MMF * DK);
#pragma unroll
  for (int p = 0; p < 4; ++p)
#pragma unroll
    for (int df = 0; df < 4; ++df)
#pragma unroll
      for (int r = 0; r < 4; ++r)
        kvo[(p * 64 + w * 16 + 4 * g + r) * DK + df * 16 + li] = kvacc[p][df][r];

  float* kso = pksum + ((size_t)sp * 64 + bh) * MMF;
#pragma unroll
  for (int p = 0; p < 4; ++p)
#pragma unroll
    for (int r = 0; r < 4; ++r) {
      float s = ksacc[p][r];
      s += __shfl_xor(s, 1); s += __shfl_xor(s, 2);
      s += __shfl_xor(s, 4); s += __shfl_xor(s, 8);
      if (li == 0) kso[p * 64 + w * 16 + 4 * g + r] = s;
    }
}

// ---------------------------------------------------------------------------
// reduce partials; emit kv TRANSPOSED bf16 kvT[bh][d][m] + ksum fp32
// ---------------------------------------------------------------------------
__global__ __launch_bounds__(256) void reduce_parts(
    const float* __restrict__ pkv, unsigned short* __restrict__ kvT,
    const float* __restrict__ pks, float* __restrict__ ksg) {
  const int id = blockIdx.x * 256 + threadIdx.x;   // grid 1024 -> 262144
  {
    const int bh = id >> 12, rest = id & 4095;
    const int m0 = (rest >> 6) << 2, d = rest & 63;
    float s0 = 0.f, s1 = 0.f, s2 = 0.f, s3 = 0.f;
#pragma unroll
    for (int sp = 0; sp < NSPLIT; ++sp) {
      const float* p = pkv + (size_t)(sp * 64 + bh) * (MMF * DK) + d;
      s0 += p[(m0 + 0) * DK]; s1 += p[(m0 + 1) * DK];
      s2 += p[(m0 + 2) * DK]; s3 += p[(m0 + 3) * DK];
    }
    ushort4 o;
    o.x = f2bf(s0); o.y = f2bf(s1); o.z = f2bf(s2); o.w = f2bf(s3);
    *(ushort4*)&kvT[((size_t)bh * DK + d) * MMF + m0] = o;
  }
  if (id < 4096) {
    float4 s = {0.f, 0.f, 0.f, 0.f};
#pragma unroll
    for (int sp = 0; sp < NSPLIT; ++sp) {
      float4 v = *(const float4*)&pks[(size_t)sp * 64 * MMF + id * 4];
      s.x += v.x; s.y += v.y; s.z += v.z; s.w += v.w;
    }
    *(float4*)&ksg[id * 4] = s;
  }
}

// ---------------------------------------------------------------------------
// q_phi + num/den -> attn (bf16). grid (64 bh, 32 l-blocks), 512 threads.
// Q frags + norms in registers; orf hi/lo + kvT + ksums RESIDENT in LDS
// (staged once); pass loop is barrier-free.
// ---------------------------------------------------------------------------
__global__ __launch_bounds__(512, 2) void qattn_mfma(
    const unsigned short* __restrict__ qhi, const unsigned short* __restrict__ qlo,
    const float* __restrict__ qnorms,
    const unsigned short* __restrict__ orfhi, const unsigned short* __restrict__ orflo,
    const unsigned short* __restrict__ kvT, const float* __restrict__ ksg,
    unsigned short* __restrict__ attn) {
  __shared__ __align__(16) unsigned short OHi[256 * 64], OLo[256 * 64];  // 32KB x2
  __shared__ __align__(16) unsigned short KvTs[64 * 256];                // 32KB
  __shared__ __align__(16) unsigned short Qphi[8][16 * 64];              // 16KB
  __shared__ float ksums[256];
  __shared__ float ns[128];
  const int tid = threadIdx.x, lane = tid & 63, w = tid >> 6;   // w: 0..7
  const int g = lane >> 4, li = lane & 15;
  const int bh = blockIdx.x, lb = blockIdx.y;
  const int b = bh >> 4, h = bh & 15;
  const int srow8 = lane >> 3;
  const int scol  = ((lane & 7) ^ srow8) << 3;
  const int sx = (li & 7) << 3;

  // ---- one-time staging ----
#pragma unroll
  for (int q = 0; q < 4; ++q) {   // orf: wave w stages rows w*32 .. w*32+31
    const size_t o = (size_t)(w * 32 + q * 8 + srow8) * 64 + scol;
    gload16(orfhi + o, &OHi[(w * 32 + q * 8) * 64]);
    gload16(orflo + o, &OLo[(w * 32 + q * 8) * 64]);
  }
  {  // kvT: 64 rows x 512B; 2 rows per gload; wave w stages rows w*8..w*8+7
    const int srow2 = lane >> 5;                  // 0..1
#pragma unroll
    for (int q = 0; q < 4; ++q) {
      const int d0 = w * 8 + q * 2, dr = d0 + srow2;
      gload16(kvT + ((size_t)bh * DK + dr) * MMF + (((lane & 31) ^ (dr & 7)) << 3),
              &KvTs[d0 * 256]);
    }
  }
  if (tid < 256) ksums[tid] = ksg[(size_t)bh * MMF + tid];
  if (tid < 128) ns[tid] = qnorms[(size_t)bh * 4096 + lb * 128 + tid];

  // Q fragments (registers): rows l = lb*128 + w*16 + li
  bf16x8 qh[2], ql[2];
  {
    const size_t qr = ((size_t)bh * 4096 + lb * 128 + w * 16 + li) * 64 + g * 8;
    qh[0] = *(const bf16x8*)&qhi[qr];
    qh[1] = *(const bf16x8*)&qhi[qr + 32];
    ql[0] = *(const bf16x8*)&qlo[qr];
    ql[1] = *(const bf16x8*)&qlo[qr + 32];
  }
  __syncthreads();

  f32x4 numacc[4] = {};
  float denacc[4] = {};

#pragma unroll
  for (int p = 0; p < 4; ++p) {
    // proj[l][m], 3-term hi/lo split; B = orf rows (pass-local m)
    f32x4 pr[4] = {};
#pragma unroll
    for (int kk = 0; kk < 2; ++kk) {
      const int cx = (kk * 32 + g * 8) ^ sx;
#pragma unroll
      for (int mf = 0; mf < 4; ++mf) {
        const int row = p * 64 + mf * 16 + li;
        const bf16x8 bh2 = *(const bf16x8*)&OHi[row * 64 + cx];
        const bf16x8 bl2 = *(const bf16x8*)&OLo[row * 64 + cx];
        pr[mf] = mfma16(qh[kk], bh2, pr[mf]);
        pr[mf] = mfma16(qh[kk], bl2, pr[mf]);
        pr[mf] = mfma16(ql[kk], bh2, pr[mf]);
      }
    }
    // phi, den partial, Qphi (wave-private, swizzled)
#pragma unroll
    for (int mf = 0; mf < 4; ++mf) {
      const float ks = ksums[p * 64 + mf * 16 + li];
#pragma unroll
      for (int r = 0; r < 4; ++r) {
        float phi = __expf(pr[mf][r] - ns[w * 16 + 4 * g + r]) + EPSF;
        denacc[r] += phi * ks;
        const int row = 4 * g + r;
        Qphi[w][row * 64 + SWZ(row, mf * 16 + li)] = f2bf(phi);
      }
    }
    // num += Qphi . kvT (same-wave Qphi; KvTs stable)
#pragma unroll
    for (int kk = 0; kk < 2; ++kk) {
      const int cx = (kk * 32 + g * 8) ^ sx;
      const bf16x8 a = *(const bf16x8*)&Qphi[w][li * 64 + cx];
#pragma unroll
      for (int df = 0; df < 4; ++df) {
        const bf16x8 bv = *(const bf16x8*)
            &KvTs[(df * 16 + li) * 256 + (((p * 8 + kk * 4 + g) ^ (li & 7)) << 3)];
        numacc[df] = mfma16(a, bv, numacc[df]);
      }
    }
  }
  float den[4];
#pragma unroll
  for (int r = 0; r < 4; ++r) {
    float s = denacc[r];
    s += __shfl_xor(s, 1); s += __shfl_xor(s, 2);
    s += __shfl_xor(s, 4); s += __shfl_xor(s, 8);
    den[r] = s;
  }
  unsigned short* ab =
      attn + ((size_t)b * 4096 + lb * 128) * 1024 + h * 64;
#pragma unroll
  for (int df = 0; df < 4; ++df)
#pragma unroll
    for (int r = 0; r < 4; ++r)
      ab[(size_t)(w * 16 + 4 * g + r) * 1024 + df * 16 + li] =
          f2bf(numacc[df][r] / den[r]);
}

// ---------------------------------------------------------------------------
extern "C" void kernel_launch(void* const* d_in, const int* in_sizes, int n_in,
                              void* d_out, int out_size, void* d_ws, size_t ws_size,
                              hipStream_t stream) {
  (void)in_sizes; (void)n_in; (void)out_size; (void)ws_size;
  const float* x   = (const float*)d_in[0];
  const float* Wq  = (const float*)d_in[1];
  const float* bq  = (const float*)d_in[2];
  const float* Wk  = (const float*)d_in[3];
  const float* bk  = (const float*)d_in[4];
  const float* Wv  = (const float*)d_in[5];
  const float* bv  = (const float*)d_in[6];
  const float* Wo  = (const float*)d_in[7];
  const float* bo  = (const float*)d_in[8];
  const float* orf = (const float*)d_in[9];
  float* out = (float*)d_out;

  const size_t ND = (size_t)BB * LL * DD;   // 16,777,216
  char* base = (char*)d_ws;
  size_t off = 0;
  auto alloc = [&](size_t bytes) -> char* {
    char* p = base + off;
    off += (bytes + 255) & ~(size_t)255;
    return p;
  };
  unsigned short* wqbf   = (unsigned short*)alloc((size_t)DD * DD * 2);
  unsigned short* wkbf   = (unsigned short*)alloc((size_t)DD * DD * 2);
  unsigned short* wvbf   = (unsigned short*)alloc((size_t)DD * DD * 2);
  unsigned short* wobf   = (unsigned short*)alloc((size_t)DD * DD * 2);
  unsigned short* orfhi  = (unsigned short*)alloc((size_t)MMF * DK * 2);
  unsigned short* orflo  = (unsigned short*)alloc((size_t)MMF * DK * 2);
  unsigned short* xbf    = (unsigned short*)alloc(ND * 2);   // aliased by pkv
  unsigned short* qhi    = (unsigned short*)alloc(ND * 2);
  unsigned short* qlo    = (unsigned short*)alloc(ND * 2);
  unsigned short* khi    = (unsigned short*)alloc(ND * 2);   // aliased by attnbf
  unsigned short* klo    = (unsigned short*)alloc(ND * 2);
  unsigned short* vtbuf  = (unsigned short*)alloc(ND * 2);
  float*          qnorms = (float*)alloc((size_t)64 * LL * 4);
  float*          knorms = (float*)alloc((size_t)64 * LL * 4);
  float*          pksum  = (float*)alloc((size_t)NSPLIT * 64 * MMF * 4);
  unsigned short* kvT    = (unsigned short*)alloc((size_t)64 * DK * MMF * 2);
  float*          ksg    = (float*)alloc((size_t)64 * MMF * 4);
  float*          pkv    = (float*)xbf;            // 33.5 MB, exact alias
  unsigned short* attnbf = khi;                    // khi dead after kv_mfma

  cvt_bf16<<<16384, 256, 0, stream>>>(x, xbf, (int)ND);
  cvt_bf16<<<1024, 256, 0, stream>>>(Wq, wqbf, DD * DD);
  cvt_bf16<<<1024, 256, 0, stream>>>(Wk, wkbf, DD * DD);
  cvt_bf16<<<1024, 256, 0, stream>>>(Wv, wvbf, DD * DD);
  cvt_bf16<<<1024, 256, 0, stream>>>(Wo, wobf, DD * DD);
  cvt_orf<<<64, 256, 0, stream>>>(orf, orfhi, orflo, MMF * DK);

  dim3 gg(128, 8);
  gemm_mfma<2><<<gg, 256, 0, stream>>>(xbf, wqbf, bq, (float*)0, qhi, qlo,
                                       qnorms, BB * LL, DD, DD);
  gemm_mfma<2><<<gg, 256, 0, stream>>>(xbf, wkbf, bk, (float*)0, khi, klo,
                                       knorms, BB * LL, DD, DD);
  gemm_mfma<1><<<gg, 256, 0, stream>>>(xbf, wvbf, bv, (float*)0, vtbuf,
                                       (unsigned short*)0, (float*)0,
                                       BB * LL, DD, DD);

  kv_mfma<<<dim3(64, NSPLIT), 256, 0, stream>>>(khi, klo, knorms, vtbuf,
                                                orfhi, orflo, pkv, pksum);
  reduce_parts<<<1024, 256, 0, stream>>>(pkv, kvT, pksum, ksg);
  qattn_mfma<<<dim3(64, 32), 512, 0, stream>>>(qhi, qlo, qnorms, orfhi, orflo,
                                               kvT, ksg, attnbf);

  gemm_mfma<0><<<gg, 256, 0, stream>>>(attnbf, wobf, bo, out, (unsigned short*)0,
                                       (unsigned short*)0, (float*)0,
                                       BB * LL, DD, DD);
}

// Round 5
// 347.286 us; speedup vs baseline: 6.9226x; 1.0498x over previous
//
#include <hip/hip_runtime.h>
#include <math.h>

// Problem constants
#define HH 16
#define BB 4
#define LL 4096
#define DD 1024
#define DK 64
#define MMF 256
#define EPSF 1e-6f
// orf scale: 64^-0.25 * log2(e)  (phi computed as exp2)
#define KSCALE (0.35355339059327373f * 1.4426950408889634f)
// norm scale: 1/(2*sqrt(64)) * log2(e)
#define NORMSCALE (0.0625f * 1.4426950408889634f)
#define NSPLIT 8
#define LCH (LL / NSPLIT)             // 512 rows of L per kv block

typedef __attribute__((ext_vector_type(8))) short bf16x8;
typedef __attribute__((ext_vector_type(4))) float f32x4;

__device__ __forceinline__ unsigned short f2bf(float f) {
  union { float f; unsigned u; } v; v.f = f;
  unsigned r = v.u + 0x7FFF + ((v.u >> 16) & 1);   // RNE
  return (unsigned short)(r >> 16);
}
__device__ __forceinline__ float bf2f(unsigned short h) {
  union { unsigned u; float f; } v; v.u = ((unsigned)h) << 16;
  return v.f;
}
__device__ __forceinline__ f32x4 mfma16(bf16x8 a, bf16x8 b, f32x4 c) {
  return __builtin_amdgcn_mfma_f32_16x16x32_bf16(a, b, c, 0, 0, 0);
}
// async global->LDS, 16B per lane; dst is wave-uniform base (lane x16 implicit)
__device__ __forceinline__ void gload16(const unsigned short* g, unsigned short* l) {
  __builtin_amdgcn_global_load_lds(
      (const __attribute__((address_space(1))) void*)g,
      (__attribute__((address_space(3))) void*)l, 16, 0, 0);
}
// T2 swizzle for 64-element bf16 rows (element-index xor)
#define SWZ(row, col) ((col) ^ (((row) & 7) << 3))

// ---------------------------------------------------------------------------
// fp32 -> bf16 conversion (n multiple of 4)
// ---------------------------------------------------------------------------
__global__ __launch_bounds__(256) void cvt_bf16(
    const float* __restrict__ src, unsigned short* __restrict__ dst, int n) {
  int i = (blockIdx.x * 256 + threadIdx.x) * 4;
  if (i < n) {
    float4 v = *(const float4*)&src[i];
    ushort4 o;
    o.x = f2bf(v.x); o.y = f2bf(v.y); o.z = f2bf(v.z); o.w = f2bf(v.w);
    *(ushort4*)&dst[i] = o;
  }
}

// orf: scale by KSCALE (dk^-.25 * log2e), split hi/lo bf16
__global__ __launch_bounds__(256) void cvt_orf(
    const float* __restrict__ src, unsigned short* __restrict__ hi,
    unsigned short* __restrict__ lo, int n) {
  int i = blockIdx.x * 256 + threadIdx.x;
  if (i < n) {
    float f = src[i] * KSCALE;
    unsigned short h = f2bf(f);
    hi[i] = h;
    lo[i] = f2bf(f - bf2f(h));
  }
}

// ---------------------------------------------------------------------------
// bf16 MFMA GEMM: C = A[M,K] @ W[N,K]^T + bias. 128x128 tile, BK=64, 4 waves.
// Fixed shape M=16384, N=1024 -> grid 128x8, XCD-swizzled.
// MODE 0: fp32 C row-major.
// MODE 1: bf16 transposed Ct[(b*16+h)*64+d][4096]                  (V path)
// MODE 2: hi/lo bf16 [bh][l][64] + norms[bh][l] (pre *log2e/16)    (Q,K paths)
// ---------------------------------------------------------------------------
template <int MODE>
__global__ __launch_bounds__(256) void gemm_mfma(
    const unsigned short* __restrict__ A, const unsigned short* __restrict__ W,
    const float* __restrict__ bias, float* __restrict__ Cf,
    unsigned short* __restrict__ C1, unsigned short* __restrict__ C2,
    float* __restrict__ Cn, int M, int N, int K) {
  __shared__ __align__(16) unsigned short As[128 * 64];
  __shared__ __align__(16) unsigned short Bs[128 * 64];
  const int tid = threadIdx.x, lane = tid & 63;
  const int w = tid >> 6, wr = w >> 1, wc = w & 1;
  const int g = lane >> 4, li = lane & 15;
  // XCD swizzle: each XCD owns 16 contiguous M-panels x all 8 N-panels
  const int flat = blockIdx.y * gridDim.x + blockIdx.x;     // 0..1023
  const int xcd = flat & 7, loc = flat >> 3;
  const int m0 = ((xcd << 4) + (loc & 15)) * 128;
  const int n0 = (loc >> 4) * 128;

  f32x4 acc[4][4] = {};
  const int srow8 = lane >> 3;                    // row within 8-row group
  const int scol  = ((lane & 7) ^ srow8) << 3;    // pre-swizzled element col
  const unsigned short* Ag = A + (size_t)(m0 + w * 32 + srow8) * K + scol;
  const unsigned short* Wg = W + (size_t)(n0 + w * 32 + srow8) * K + scol;

  for (int k0 = 0; k0 < K; k0 += 64) {
    __syncthreads();
#pragma unroll
    for (int j = 0; j < 4; ++j) {
      gload16(Ag + (size_t)j * 8 * K + k0, &As[(w * 32 + j * 8) * 64]);
      gload16(Wg + (size_t)j * 8 * K + k0, &Bs[(w * 32 + j * 8) * 64]);
    }
    __syncthreads();
    const int sx = (li & 7) << 3;
#pragma unroll
    for (int kk = 0; kk < 2; ++kk) {
      const int c = (kk * 32 + g * 8) ^ sx;
      bf16x8 af[4], bfr[4];
#pragma unroll
      for (int i = 0; i < 4; ++i)
        af[i] = *(const bf16x8*)&As[(wr * 64 + i * 16 + li) * 64 + c];
#pragma unroll
      for (int j = 0; j < 4; ++j)
        bfr[j] = *(const bf16x8*)&Bs[(wc * 64 + j * 16 + li) * 64 + c];
#pragma unroll
      for (int i = 0; i < 4; ++i)
#pragma unroll
        for (int j = 0; j < 4; ++j)
          acc[i][j] = mfma16(af[i], bfr[j], acc[i][j]);
    }
  }

  if (MODE == 2) {
    const int head = (n0 + wc * 64) >> 6;
#pragma unroll
    for (int i = 0; i < 4; ++i) {
      const int rr = m0 + wr * 64 + i * 16 + 4 * g;
      const int b = rr >> 12, l = rr & 4095;
      const size_t rowb = (size_t)(b * 16 + head) * 4096 + l;
      float np[4] = {0.f, 0.f, 0.f, 0.f};
#pragma unroll
      for (int j = 0; j < 4; ++j) {
        const float bz = bias[n0 + wc * 64 + j * 16 + li];
        const int d = j * 16 + li;
#pragma unroll
        for (int r = 0; r < 4; ++r) {
          float v = acc[i][j][r] + bz;
          np[r] += v * v;
          unsigned short hv = f2bf(v);
          C1[(rowb + r) * 64 + d] = hv;
          C2[(rowb + r) * 64 + d] = f2bf(v - bf2f(hv));
        }
      }
#pragma unroll
      for (int r = 0; r < 4; ++r) {
        float s = np[r];
        s += __shfl_xor(s, 1); s += __shfl_xor(s, 2);
        s += __shfl_xor(s, 4); s += __shfl_xor(s, 8);
        if (li == 0) Cn[rowb + r] = s * NORMSCALE;
      }
    }
  } else {
#pragma unroll
    for (int i = 0; i < 4; ++i) {
      const int rr = m0 + wr * 64 + i * 16 + 4 * g;
#pragma unroll
      for (int j = 0; j < 4; ++j) {
        const int cc = n0 + wc * 64 + j * 16 + li;
        const float bz = bias[cc];
        if (MODE == 1) {
          const int b = rr >> 12, l = rr & 4095;
          ushort4 o;
          o.x = f2bf(acc[i][j][0] + bz); o.y = f2bf(acc[i][j][1] + bz);
          o.z = f2bf(acc[i][j][2] + bz); o.w = f2bf(acc[i][j][3] + bz);
          *(ushort4*)&C1[((size_t)b * 1024 + cc) * 4096 + l] = o;
        } else {
#pragma unroll
          for (int r = 0; r < 4; ++r)
            Cf[(size_t)(rr + r) * N + cc] = acc[i][j][r] + bz;
        }
      }
    }
  }
}

// ---------------------------------------------------------------------------
// kv + ksum. grid (64 bh, NSPLIT). orf hi/lo fragments in REGISTERS (3-term
// split); K hi/lo, V^T staged via gload16; barrier-free 4-pass inner loop.
// ---------------------------------------------------------------------------
__global__ __launch_bounds__(256, 2) void kv_mfma(
    const unsigned short* __restrict__ khi, const unsigned short* __restrict__ klo,
    const float* __restrict__ knorms, const unsigned short* __restrict__ vt,
    const unsigned short* __restrict__ orfhi, const unsigned short* __restrict__ orflo,
    float* __restrict__ pkv, float* __restrict__ pksum) {
  __shared__ __align__(16) unsigned short KsHi[64 * 64], KsLo[64 * 64];
  __shared__ __align__(16) unsigned short VT[64 * 64], KphiT[64 * 64];
  __shared__ float ns[64];
  const int tid = threadIdx.x, lane = tid & 63, w = tid >> 6;
  const int g = lane >> 4, li = lane & 15;
  const int bh = blockIdx.x, sp = blockIdx.y;
  const int srow8 = lane >> 3;
  const int scol  = ((lane & 7) ^ srow8) << 3;
  const int sx = (li & 7) << 3;

  // orf fragments in registers: A-operand rows m = p*64 + w*16 + li
  bf16x8 oh[4][2], ol[4][2];
#pragma unroll
  for (int p = 0; p < 4; ++p)
#pragma unroll
    for (int kk = 0; kk < 2; ++kk) {
      const size_t o = (size_t)(p * 64 + w * 16 + li) * 64 + kk * 32 + g * 8;
      oh[p][kk] = *(const bf16x8*)&orfhi[o];
      ol[p][kk] = *(const bf16x8*)&orflo[o];
    }

  f32x4 kvacc[4][4] = {};
  float ksacc[4][4] = {};

  for (int c = 0; c < LCH / 64; ++c) {
    const int l0 = sp * LCH + c * 64;
    __syncthreads();   // previous chunk's readers done
    {  // stage K hi/lo + V^T via gload (pre-swizzled source, linear LDS)
      const size_t kb = ((size_t)bh * 4096 + l0 + w * 16 + srow8) * 64 + scol;
      gload16(khi + kb, &KsHi[(w * 16) * 64]);
      gload16(khi + kb + 8 * 64, &KsHi[(w * 16 + 8) * 64]);
      gload16(klo + kb, &KsLo[(w * 16) * 64]);
      gload16(klo + kb + 8 * 64, &KsLo[(w * 16 + 8) * 64]);
      const size_t vb = ((size_t)bh * 64 + w * 16 + srow8) * 4096 + l0 + scol;
      gload16(vt + vb, &VT[(w * 16) * 64]);
      gload16(vt + vb + (size_t)8 * 4096, &VT[(w * 16 + 8) * 64]);
      if (tid < 64) ns[tid] = knorms[(size_t)bh * 4096 + l0 + tid];
    }
    __syncthreads();

#pragma unroll
    for (int p = 0; p < 4; ++p) {
      // projT[m][l], 3-term hi/lo split
      f32x4 pr[4] = {};
      __builtin_amdgcn_s_setprio(1);
#pragma unroll
      for (int kk = 0; kk < 2; ++kk) {
        const int cx = (kk * 32 + g * 8) ^ sx;
#pragma unroll
        for (int lf = 0; lf < 4; ++lf) {
          const bf16x8 bh2 = *(const bf16x8*)&KsHi[(lf * 16 + li) * 64 + cx];
          const bf16x8 bl2 = *(const bf16x8*)&KsLo[(lf * 16 + li) * 64 + cx];
          pr[lf] = mfma16(oh[p][kk], bh2, pr[lf]);
          pr[lf] = mfma16(oh[p][kk], bl2, pr[lf]);
          pr[lf] = mfma16(ol[p][kk], bh2, pr[lf]);
        }
      }
      __builtin_amdgcn_s_setprio(0);
      // phi (exp2) + ksum + KphiT (wave-private rows, swizzled)
#pragma unroll
      for (int lf = 0; lf < 4; ++lf) {
        const float nrm = ns[lf * 16 + li];
#pragma unroll
        for (int r = 0; r < 4; ++r) {
          float phi = exp2f(pr[lf][r] - nrm) + EPSF;
          ksacc[p][r] += phi;
          const int row = w * 16 + 4 * g + r;
          KphiT[row * 64 + SWZ(row, lf * 16 + li)] = f2bf(phi);
        }
      }
      // kv += KphiT . V^T (same-wave LDS dependence, no barrier)
      __builtin_amdgcn_s_setprio(1);
#pragma unroll
      for (int kk = 0; kk < 2; ++kk) {
        const int cx = (kk * 32 + g * 8) ^ sx;
        const bf16x8 a = *(const bf16x8*)&KphiT[(w * 16 + li) * 64 + cx];
#pragma unroll
        for (int df = 0; df < 4; ++df) {
          const bf16x8 bv = *(const bf16x8*)&VT[(df * 16 + li) * 64 + cx];
          kvacc[p][df] = mfma16(a, bv, kvacc[p][df]);
        }
      }
      __builtin_amdgcn_s_setprio(0);
    }
  }
  float* kvo = pkv + ((size_t)sp * 64 + bh) * (MMF * DK);
#pragma unroll
  for (int p = 0; p < 4; ++p)
#pragma unroll
    for (int df = 0; df < 4; ++df)
#pragma unroll
      for (int r = 0; r < 4; ++r)
        kvo[(p * 64 + w * 16 + 4 * g + r) * DK + df * 16 + li] = kvacc[p][df][r];

  float* kso = pksum + ((size_t)sp * 64 + bh) * MMF;
#pragma unroll
  for (int p = 0; p < 4; ++p)
#pragma unroll
    for (int r = 0; r < 4; ++r) {
      float s = ksacc[p][r];
      s += __shfl_xor(s, 1); s += __shfl_xor(s, 2);
      s += __shfl_xor(s, 4); s += __shfl_xor(s, 8);
      if (li == 0) kso[p * 64 + w * 16 + 4 * g + r] = s;
    }
}

// ---------------------------------------------------------------------------
// reduce partials; emit kv TRANSPOSED bf16 kvT[bh][d][m] + ksum fp32
// ---------------------------------------------------------------------------
__global__ __launch_bounds__(256) void reduce_parts(
    const float* __restrict__ pkv, unsigned short* __restrict__ kvT,
    const float* __restrict__ pks, float* __restrict__ ksg) {
  const int id = blockIdx.x * 256 + threadIdx.x;   // grid 1024 -> 262144
  {
    const int bh = id >> 12, rest = id & 4095;
    const int m0 = (rest >> 6) << 2, d = rest & 63;
    float s0 = 0.f, s1 = 0.f, s2 = 0.f, s3 = 0.f;
#pragma unroll
    for (int sp = 0; sp < NSPLIT; ++sp) {
      const float* p = pkv + (size_t)(sp * 64 + bh) * (MMF * DK) + d;
      s0 += p[(m0 + 0) * DK]; s1 += p[(m0 + 1) * DK];
      s2 += p[(m0 + 2) * DK]; s3 += p[(m0 + 3) * DK];
    }
    ushort4 o;
    o.x = f2bf(s0); o.y = f2bf(s1); o.z = f2bf(s2); o.w = f2bf(s3);
    *(ushort4*)&kvT[((size_t)bh * DK + d) * MMF + m0] = o;
  }
  if (id < 4096) {
    float4 s = {0.f, 0.f, 0.f, 0.f};
#pragma unroll
    for (int sp = 0; sp < NSPLIT; ++sp) {
      float4 v = *(const float4*)&pks[(size_t)sp * 64 * MMF + id * 4];
      s.x += v.x; s.y += v.y; s.z += v.z; s.w += v.w;
    }
    *(float4*)&ksg[id * 4] = s;
  }
}

// ---------------------------------------------------------------------------
// q_phi + num/den -> attn (bf16). grid (64 bh, 32 l-blocks), 512 threads.
// 2-term proj split (orf-lo dropped). Q frags / norms / ksums in registers;
// OHi + kvT resident in LDS (80KB exactly -> 2 blocks/CU); barrier-free loop.
// ---------------------------------------------------------------------------
__global__ __launch_bounds__(512, 4) void qattn_mfma(
    const unsigned short* __restrict__ qhi, const unsigned short* __restrict__ qlo,
    const float* __restrict__ qnorms,
    const unsigned short* __restrict__ orfhi,
    const unsigned short* __restrict__ kvT, const float* __restrict__ ksg,
    unsigned short* __restrict__ attn) {
  __shared__ __align__(16) unsigned short OHi[256 * 64];    // 32 KB
  __shared__ __align__(16) unsigned short KvTs[64 * 256];   // 32 KB
  __shared__ __align__(16) unsigned short Qphi[8][16 * 64]; // 16 KB  -> 80 KB total
  const int tid = threadIdx.x, lane = tid & 63, w = tid >> 6;   // w: 0..7
  const int g = lane >> 4, li = lane & 15;
  const int bh = blockIdx.x, lb = blockIdx.y;
  const int b = bh >> 4, h = bh & 15;
  const int srow8 = lane >> 3;
  const int scol  = ((lane & 7) ^ srow8) << 3;
  const int sx = (li & 7) << 3;

  // ---- one-time staging ----
#pragma unroll
  for (int q = 0; q < 4; ++q) {   // orf-hi: wave w stages rows w*32 .. w*32+31
    const size_t o = (size_t)(w * 32 + q * 8 + srow8) * 64 + scol;
    gload16(orfhi + o, &OHi[(w * 32 + q * 8) * 64]);
  }
  {  // kvT: 64 rows x 512B; 2 rows per gload; wave w stages rows w*8..w*8+7
    const int srow2 = lane >> 5;                  // 0..1
#pragma unroll
    for (int q = 0; q < 4; ++q) {
      const int d0 = w * 8 + q * 2, dr = d0 + srow2;
      gload16(kvT + ((size_t)bh * DK + dr) * MMF + (((lane & 31) ^ (dr & 7)) << 3),
              &KvTs[d0 * 256]);
    }
  }

  // registers: ksums, norms, Q fragments
  float ksr[4][4];
#pragma unroll
  for (int p = 0; p < 4; ++p)
#pragma unroll
    for (int mf = 0; mf < 4; ++mf)
      ksr[p][mf] = ksg[(size_t)bh * MMF + p * 64 + mf * 16 + li];
  const float4 nr =
      *(const float4*)&qnorms[(size_t)bh * 4096 + lb * 128 + w * 16 + 4 * g];
  bf16x8 qh[2], ql[2];
  {
    const size_t qr = ((size_t)bh * 4096 + lb * 128 + w * 16 + li) * 64 + g * 8;
    qh[0] = *(const bf16x8*)&qhi[qr];
    qh[1] = *(const bf16x8*)&qhi[qr + 32];
    ql[0] = *(const bf16x8*)&qlo[qr];
    ql[1] = *(const bf16x8*)&qlo[qr + 32];
  }
  __syncthreads();   // gload staging complete

  f32x4 numacc[4] = {};
  float denacc[4] = {};

#pragma unroll
  for (int p = 0; p < 4; ++p) {
    // proj[l][m], 2-term split (qh*oh + ql*oh)
    f32x4 pr[4] = {};
    __builtin_amdgcn_s_setprio(1);
#pragma unroll
    for (int kk = 0; kk < 2; ++kk) {
      const int cx = (kk * 32 + g * 8) ^ sx;
#pragma unroll
      for (int mf = 0; mf < 4; ++mf) {
        const int row = p * 64 + mf * 16 + li;
        const bf16x8 bh2 = *(const bf16x8*)&OHi[row * 64 + cx];
        pr[mf] = mfma16(qh[kk], bh2, pr[mf]);
        pr[mf] = mfma16(ql[kk], bh2, pr[mf]);
      }
    }
    __builtin_amdgcn_s_setprio(0);
    // phi (exp2), den partial, Qphi (wave-private, swizzled)
#pragma unroll
    for (int mf = 0; mf < 4; ++mf) {
      const float ks = ksr[p][mf];
#pragma unroll
      for (int r = 0; r < 4; ++r) {
        float phi = exp2f(pr[mf][r] - nr[r]) + EPSF;
        denacc[r] += phi * ks;
        const int row = 4 * g + r;
        Qphi[w][row * 64 + SWZ(row, mf * 16 + li)] = f2bf(phi);
      }
    }
    // num += Qphi . kvT (same-wave Qphi; KvTs stable)
    __builtin_amdgcn_s_setprio(1);
#pragma unroll
    for (int kk = 0; kk < 2; ++kk) {
      const int cx = (kk * 32 + g * 8) ^ sx;
      const bf16x8 a = *(const bf16x8*)&Qphi[w][li * 64 + cx];
#pragma unroll
      for (int df = 0; df < 4; ++df) {
        const bf16x8 bv = *(const bf16x8*)
            &KvTs[(df * 16 + li) * 256 + (((p * 8 + kk * 4 + g) ^ (li & 7)) << 3)];
        numacc[df] = mfma16(a, bv, numacc[df]);
      }
    }
    __builtin_amdgcn_s_setprio(0);
  }
  float den[4];
#pragma unroll
  for (int r = 0; r < 4; ++r) {
    float s = denacc[r];
    s += __shfl_xor(s, 1); s += __shfl_xor(s, 2);
    s += __shfl_xor(s, 4); s += __shfl_xor(s, 8);
    den[r] = s;
  }
  unsigned short* ab =
      attn + ((size_t)b * 4096 + lb * 128) * 1024 + h * 64;
#pragma unroll
  for (int df = 0; df < 4; ++df)
#pragma unroll
    for (int r = 0; r < 4; ++r)
      ab[(size_t)(w * 16 + 4 * g + r) * 1024 + df * 16 + li] =
          f2bf(numacc[df][r] / den[r]);
}

// ---------------------------------------------------------------------------
extern "C" void kernel_launch(void* const* d_in, const int* in_sizes, int n_in,
                              void* d_out, int out_size, void* d_ws, size_t ws_size,
                              hipStream_t stream) {
  (void)in_sizes; (void)n_in; (void)out_size; (void)ws_size;
  const float* x   = (const float*)d_in[0];
  const float* Wq  = (const float*)d_in[1];
  const float* bq  = (const float*)d_in[2];
  const float* Wk  = (const float*)d_in[3];
  const float* bk  = (const float*)d_in[4];
  const float* Wv  = (const float*)d_in[5];
  const float* bv  = (const float*)d_in[6];
  const float* Wo  = (const float*)d_in[7];
  const float* bo  = (const float*)d_in[8];
  const float* orf = (const float*)d_in[9];
  float* out = (float*)d_out;

  const size_t ND = (size_t)BB * LL * DD;   // 16,777,216
  char* base = (char*)d_ws;
  size_t off = 0;
  auto alloc = [&](size_t bytes) -> char* {
    char* p = base + off;
    off += (bytes + 255) & ~(size_t)255;
    return p;
  };
  unsigned short* wqbf   = (unsigned short*)alloc((size_t)DD * DD * 2);
  unsigned short* wkbf   = (unsigned short*)alloc((size_t)DD * DD * 2);
  unsigned short* wvbf   = (unsigned short*)alloc((size_t)DD * DD * 2);
  unsigned short* wobf   = (unsigned short*)alloc((size_t)DD * DD * 2);
  unsigned short* orfhi  = (unsigned short*)alloc((size_t)MMF * DK * 2);
  unsigned short* orflo  = (unsigned short*)alloc((size_t)MMF * DK * 2);
  unsigned short* xbf    = (unsigned short*)alloc(ND * 2);   // aliased by pkv
  unsigned short* qhi    = (unsigned short*)alloc(ND * 2);
  unsigned short* qlo    = (unsigned short*)alloc(ND * 2);
  unsigned short* khi    = (unsigned short*)alloc(ND * 2);   // aliased by attnbf
  unsigned short* klo    = (unsigned short*)alloc(ND * 2);
  unsigned short* vtbuf  = (unsigned short*)alloc(ND * 2);
  float*          qnorms = (float*)alloc((size_t)64 * LL * 4);
  float*          knorms = (float*)alloc((size_t)64 * LL * 4);
  float*          pksum  = (float*)alloc((size_t)NSPLIT * 64 * MMF * 4);
  unsigned short* kvT    = (unsigned short*)alloc((size_t)64 * DK * MMF * 2);
  float*          ksg    = (float*)alloc((size_t)64 * MMF * 4);
  float*          pkv    = (float*)xbf;            // 33.5 MB, exact alias
  unsigned short* attnbf = khi;                    // khi dead after kv_mfma

  cvt_bf16<<<16384, 256, 0, stream>>>(x, xbf, (int)ND);
  cvt_bf16<<<1024, 256, 0, stream>>>(Wq, wqbf, DD * DD);
  cvt_bf16<<<1024, 256, 0, stream>>>(Wk, wkbf, DD * DD);
  cvt_bf16<<<1024, 256, 0, stream>>>(Wv, wvbf, DD * DD);
  cvt_bf16<<<1024, 256, 0, stream>>>(Wo, wobf, DD * DD);
  cvt_orf<<<64, 256, 0, stream>>>(orf, orfhi, orflo, MMF * DK);

  dim3 gg(128, 8);
  gemm_mfma<2><<<gg, 256, 0, stream>>>(xbf, wqbf, bq, (float*)0, qhi, qlo,
                                       qnorms, BB * LL, DD, DD);
  gemm_mfma<2><<<gg, 256, 0, stream>>>(xbf, wkbf, bk, (float*)0, khi, klo,
                                       knorms, BB * LL, DD, DD);
  gemm_mfma<1><<<gg, 256, 0, stream>>>(xbf, wvbf, bv, (float*)0, vtbuf,
                                       (unsigned short*)0, (float*)0,
                                       BB * LL, DD, DD);

  kv_mfma<<<dim3(64, NSPLIT), 256, 0, stream>>>(khi, klo, knorms, vtbuf,
                                                orfhi, orflo, pkv, pksum);
  reduce_parts<<<1024, 256, 0, stream>>>(pkv, kvT, pksum, ksg);
  qattn_mfma<<<dim3(64, 32), 512, 0, stream>>>(qhi, qlo, qnorms, orfhi,
                                               kvT, ksg, attnbf);

  gemm_mfma<0><<<gg, 256, 0, stream>>>(attnbf, wobf, bo, out, (unsigned short*)0,
                                       (unsigned short*)0, (float*)0,
                                       BB * LL, DD, DD);
}

// Round 6
// 341.925 us; speedup vs baseline: 7.0311x; 1.0157x over previous
//
#include <hip/hip_runtime.h>
#include <math.h>

// Problem constants
#define HH 16
#define BB 4
#define LL 4096
#define DD 1024
#define DK 64
#define MMF 256
#define EPSF 1e-6f
// orf scale: 64^-0.25 * log2(e)  (phi computed as exp2)
#define KSCALE (0.35355339059327373f * 1.4426950408889634f)
// norm scale: 1/(2*sqrt(64)) * log2(e)
#define NORMSCALE (0.0625f * 1.4426950408889634f)
#define NSPLIT 8
#define LCH (LL / NSPLIT)             // 512 rows of L per kv block

typedef __attribute__((ext_vector_type(8))) short bf16x8;
typedef __attribute__((ext_vector_type(4))) float f32x4;
typedef __attribute__((ext_vector_type(8))) unsigned short u16x8;

__device__ __forceinline__ unsigned short f2bf(float f) {
  union { float f; unsigned u; } v; v.f = f;
  unsigned r = v.u + 0x7FFF + ((v.u >> 16) & 1);   // RNE
  return (unsigned short)(r >> 16);
}
__device__ __forceinline__ float bf2f(unsigned short h) {
  union { unsigned u; float f; } v; v.u = ((unsigned)h) << 16;
  return v.f;
}
__device__ __forceinline__ f32x4 mfma16(bf16x8 a, bf16x8 b, f32x4 c) {
  return __builtin_amdgcn_mfma_f32_16x16x32_bf16(a, b, c, 0, 0, 0);
}
// async global->LDS, 16B per lane; dst is wave-uniform base (lane x16 implicit)
__device__ __forceinline__ void gload16(const unsigned short* g, unsigned short* l) {
  __builtin_amdgcn_global_load_lds(
      (const __attribute__((address_space(1))) void*)g,
      (__attribute__((address_space(3))) void*)l, 16, 0, 0);
}
// T2 swizzle for 64-element bf16 rows (element-index xor)
#define SWZ(row, col) ((col) ^ (((row) & 7) << 3))

// ---------------------------------------------------------------------------
// fp32 -> bf16 conversion (n multiple of 4)
// ---------------------------------------------------------------------------
__global__ __launch_bounds__(256) void cvt_bf16(
    const float* __restrict__ src, unsigned short* __restrict__ dst, int n) {
  int i = (blockIdx.x * 256 + threadIdx.x) * 4;
  if (i < n) {
    float4 v = *(const float4*)&src[i];
    ushort4 o;
    o.x = f2bf(v.x); o.y = f2bf(v.y); o.z = f2bf(v.z); o.w = f2bf(v.w);
    *(ushort4*)&dst[i] = o;
  }
}

// fused 4-way weight conversion, grid (1024, 4)
__global__ __launch_bounds__(256) void cvt_bf16_w(
    const float* __restrict__ W0, const float* __restrict__ W1,
    const float* __restrict__ W2, const float* __restrict__ W3,
    unsigned short* __restrict__ D0, unsigned short* __restrict__ D1,
    unsigned short* __restrict__ D2, unsigned short* __restrict__ D3) {
  const float* s;
  unsigned short* d;
  switch (blockIdx.y) {
    case 0: s = W0; d = D0; break;
    case 1: s = W1; d = D1; break;
    case 2: s = W2; d = D2; break;
    default: s = W3; d = D3; break;
  }
  int i = (blockIdx.x * 256 + threadIdx.x) * 4;
  float4 v = *(const float4*)&s[i];
  ushort4 o;
  o.x = f2bf(v.x); o.y = f2bf(v.y); o.z = f2bf(v.z); o.w = f2bf(v.w);
  *(ushort4*)&d[i] = o;
}

// orf: scale by KSCALE (dk^-.25 * log2e), split hi/lo bf16
__global__ __launch_bounds__(256) void cvt_orf(
    const float* __restrict__ src, unsigned short* __restrict__ hi,
    unsigned short* __restrict__ lo, int n) {
  int i = blockIdx.x * 256 + threadIdx.x;
  if (i < n) {
    float f = src[i] * KSCALE;
    unsigned short h = f2bf(f);
    hi[i] = h;
    lo[i] = f2bf(f - bf2f(h));
  }
}

// ---------------------------------------------------------------------------
// bf16 MFMA GEMM: C = A[M,K] @ W[N,K]^T + bias. 128x128 tile, BK=64, 4 waves.
// Fixed shape M=16384, N=1024 -> grid 128x8, XCD-swizzled.
// Epilogue: per-wave LDS-transpose -> fully coalesced 16B vector stores.
// MODE 0: fp32 C row-major.
// MODE 1: bf16 transposed Ct[(b*16+h)*64+d][4096]                  (V path)
// MODE 2: hi/lo bf16 [bh][l][64] + norms[bh][l] (pre *log2e/16)    (Q,K paths)
// ---------------------------------------------------------------------------
template <int MODE>
__global__ __launch_bounds__(256) void gemm_mfma(
    const unsigned short* __restrict__ A, const unsigned short* __restrict__ W,
    const float* __restrict__ bias, float* __restrict__ Cf,
    unsigned short* __restrict__ C1, unsigned short* __restrict__ C2,
    float* __restrict__ Cn, int M, int N, int K) {
  // union: staging (As 16KB + Bs 16KB) / epilogue (4 waves x 32x68 f32 = 34816B)
  __shared__ __align__(16) char smem[4 * 32 * 68 * 4];
  unsigned short* As = (unsigned short*)smem;
  unsigned short* Bs = (unsigned short*)(smem + 16384);
  const int tid = threadIdx.x, lane = tid & 63;
  const int w = tid >> 6, wr = w >> 1, wc = w & 1;
  const int g = lane >> 4, li = lane & 15;
  // XCD swizzle: each XCD owns 16 contiguous M-panels x all 8 N-panels
  const int flat = blockIdx.y * gridDim.x + blockIdx.x;     // 0..1023
  const int xcd = flat & 7, loc = flat >> 3;
  const int m0 = ((xcd << 4) + (loc & 15)) * 128;
  const int n0 = (loc >> 4) * 128;

  f32x4 acc[4][4] = {};
  const int srow8 = lane >> 3;                    // row within 8-row group
  const int scol  = ((lane & 7) ^ srow8) << 3;    // pre-swizzled element col
  const unsigned short* Ag = A + (size_t)(m0 + w * 32 + srow8) * K + scol;
  const unsigned short* Wg = W + (size_t)(n0 + w * 32 + srow8) * K + scol;

  for (int k0 = 0; k0 < K; k0 += 64) {
    __syncthreads();
#pragma unroll
    for (int j = 0; j < 4; ++j) {
      gload16(Ag + (size_t)j * 8 * K + k0, &As[(w * 32 + j * 8) * 64]);
      gload16(Wg + (size_t)j * 8 * K + k0, &Bs[(w * 32 + j * 8) * 64]);
    }
    __syncthreads();
    const int sx = (li & 7) << 3;
#pragma unroll
    for (int kk = 0; kk < 2; ++kk) {
      const int c = (kk * 32 + g * 8) ^ sx;
      bf16x8 af[4], bfr[4];
#pragma unroll
      for (int i = 0; i < 4; ++i)
        af[i] = *(const bf16x8*)&As[(wr * 64 + i * 16 + li) * 64 + c];
#pragma unroll
      for (int j = 0; j < 4; ++j)
        bfr[j] = *(const bf16x8*)&Bs[(wc * 64 + j * 16 + li) * 64 + c];
#pragma unroll
      for (int i = 0; i < 4; ++i)
#pragma unroll
        for (int j = 0; j < 4; ++j)
          acc[i][j] = mfma16(af[i], bfr[j], acc[i][j]);
    }
  }

  // ---------------- epilogue: LDS transpose, coalesced stores ---------------
  __syncthreads();   // all waves done reading As/Bs
  float* ep = (float*)smem + w * (32 * 68);
  const int head = (n0 + wc * 64) >> 6;
  const int rbase = m0 + wr * 64;       // global row base of this wave's tile
  const int b = rbase >> 12;            // batch (tile never crosses b boundary)

  if (MODE == 2) {
#pragma unroll
    for (int jh = 0; jh < 2; ++jh) {
      // write half: local rows 0..31 = global rows jh*32..+31, all 64 cols
#pragma unroll
      for (int i2 = 0; i2 < 2; ++i2) {
        const int i = jh * 2 + i2;
#pragma unroll
        for (int j = 0; j < 4; ++j) {
          const float bz = bias[n0 + wc * 64 + j * 16 + li];
#pragma unroll
          for (int r = 0; r < 4; ++r)
            ep[(i2 * 16 + 4 * g + r) * 68 + j * 16 + li] = acc[i][j][r] + bz;
        }
      }
      // read half: lane -> (row = p*8 + lane>>3, chunk c = lane&7 of 8 f32)
      const int rrow = lane >> 3, cc = lane & 7;
#pragma unroll
      for (int p = 0; p < 4; ++p) {
        const int row = p * 8 + rrow;
        float v[8];
        *(f32x4*)&v[0] = *(const f32x4*)&ep[row * 68 + cc * 8];
        *(f32x4*)&v[4] = *(const f32x4*)&ep[row * 68 + cc * 8 + 4];
        float np = 0.f;
        u16x8 hv, lv;
#pragma unroll
        for (int e = 0; e < 8; ++e) {
          float vv = v[e];
          np += vv * vv;
          unsigned short h = f2bf(vv);
          hv[e] = h;
          lv[e] = f2bf(vv - bf2f(h));
        }
        const int lg = (rbase + jh * 32 + row) & 4095;
        const size_t rowb = (size_t)(b * 16 + head) * 4096 + lg;
        *(u16x8*)&C1[rowb * 64 + cc * 8] = hv;
        *(u16x8*)&C2[rowb * 64 + cc * 8] = lv;
        np += __shfl_xor(np, 1);
        np += __shfl_xor(np, 2);
        np += __shfl_xor(np, 4);
        if (cc == 0) Cn[rowb] = np * NORMSCALE;
      }
    }
  } else if (MODE == 1) {
#pragma unroll
    for (int jh = 0; jh < 2; ++jh) {
      // write half: LDS [32 d][68 l]; acc's 4 rows (l) contiguous -> b128
#pragma unroll
      for (int i = 0; i < 4; ++i)
#pragma unroll
        for (int j2 = 0; j2 < 2; ++j2) {
          const int j = jh * 2 + j2;
          const float bz = bias[n0 + wc * 64 + j * 16 + li];
          f32x4 t;
          t[0] = acc[i][j][0] + bz; t[1] = acc[i][j][1] + bz;
          t[2] = acc[i][j][2] + bz; t[3] = acc[i][j][3] + bz;
          *(f32x4*)&ep[(j2 * 16 + li) * 68 + i * 16 + 4 * g] = t;
        }
      // read half: lane -> (d = p*8 + lane>>3, chunk c = lane&7 of 8 l)
      const int rd = lane >> 3, cc = lane & 7;
#pragma unroll
      for (int p = 0; p < 4; ++p) {
        const int dl = p * 8 + rd;
        float v[8];
        *(f32x4*)&v[0] = *(const f32x4*)&ep[dl * 68 + cc * 8];
        *(f32x4*)&v[4] = *(const f32x4*)&ep[dl * 68 + cc * 8 + 4];
        u16x8 hv;
#pragma unroll
        for (int e = 0; e < 8; ++e) hv[e] = f2bf(v[e]);
        const int dh = jh * 32 + dl;
        const int lg = rbase & 4095;
        *(u16x8*)&C1[((size_t)(b * 16 + head) * 64 + dh) * 4096 + lg + cc * 8] = hv;
      }
    }
  } else {  // MODE 0: fp32 row-major
#pragma unroll
    for (int jh = 0; jh < 2; ++jh) {
#pragma unroll
      for (int i2 = 0; i2 < 2; ++i2) {
        const int i = jh * 2 + i2;
#pragma unroll
        for (int j = 0; j < 4; ++j) {
          const float bz = bias[n0 + wc * 64 + j * 16 + li];
#pragma unroll
          for (int r = 0; r < 4; ++r)
            ep[(i2 * 16 + 4 * g + r) * 68 + j * 16 + li] = acc[i][j][r] + bz;
        }
      }
      // read: lane -> (row = p*4 + lane>>4, chunk c = lane&15 of 4 f32)
      const int rrow = lane >> 4, cc = lane & 15;
#pragma unroll
      for (int p = 0; p < 8; ++p) {
        const int row = p * 4 + rrow;
        f32x4 v = *(const f32x4*)&ep[row * 68 + cc * 4];
        *(f32x4*)&Cf[(size_t)(rbase + jh * 32 + row) * 1024 + n0 + wc * 64 + cc * 4] = v;
      }
    }
  }
}

// ---------------------------------------------------------------------------
// kv + ksum. grid (64 bh, NSPLIT). orf hi/lo fragments in REGISTERS (3-term
// split); K hi/lo, V^T staged via gload16; barrier-free 4-pass inner loop.
// ---------------------------------------------------------------------------
__global__ __launch_bounds__(256, 2) void kv_mfma(
    const unsigned short* __restrict__ khi, const unsigned short* __restrict__ klo,
    const float* __restrict__ knorms, const unsigned short* __restrict__ vt,
    const unsigned short* __restrict__ orfhi, const unsigned short* __restrict__ orflo,
    float* __restrict__ pkv, float* __restrict__ pksum) {
  __shared__ __align__(16) unsigned short KsHi[64 * 64], KsLo[64 * 64];
  __shared__ __align__(16) unsigned short VT[64 * 64], KphiT[64 * 64];
  __shared__ float ns[64];
  const int tid = threadIdx.x, lane = tid & 63, w = tid >> 6;
  const int g = lane >> 4, li = lane & 15;
  const int bh = blockIdx.x, sp = blockIdx.y;
  const int srow8 = lane >> 3;
  const int scol  = ((lane & 7) ^ srow8) << 3;
  const int sx = (li & 7) << 3;

  // orf fragments in registers: A-operand rows m = p*64 + w*16 + li
  bf16x8 oh[4][2], ol[4][2];
#pragma unroll
  for (int p = 0; p < 4; ++p)
#pragma unroll
    for (int kk = 0; kk < 2; ++kk) {
      const size_t o = (size_t)(p * 64 + w * 16 + li) * 64 + kk * 32 + g * 8;
      oh[p][kk] = *(const bf16x8*)&orfhi[o];
      ol[p][kk] = *(const bf16x8*)&orflo[o];
    }

  f32x4 kvacc[4][4] = {};
  float ksacc[4][4] = {};

  for (int c = 0; c < LCH / 64; ++c) {
    const int l0 = sp * LCH + c * 64;
    __syncthreads();   // previous chunk's readers done
    {  // stage K hi/lo + V^T via gload (pre-swizzled source, linear LDS)
      const size_t kb = ((size_t)bh * 4096 + l0 + w * 16 + srow8) * 64 + scol;
      gload16(khi + kb, &KsHi[(w * 16) * 64]);
      gload16(khi + kb + 8 * 64, &KsHi[(w * 16 + 8) * 64]);
      gload16(klo + kb, &KsLo[(w * 16) * 64]);
      gload16(klo + kb + 8 * 64, &KsLo[(w * 16 + 8) * 64]);
      const size_t vb = ((size_t)bh * 64 + w * 16 + srow8) * 4096 + l0 + scol;
      gload16(vt + vb, &VT[(w * 16) * 64]);
      gload16(vt + vb + (size_t)8 * 4096, &VT[(w * 16 + 8) * 64]);
      if (tid < 64) ns[tid] = knorms[(size_t)bh * 4096 + l0 + tid];
    }
    __syncthreads();

#pragma unroll
    for (int p = 0; p < 4; ++p) {
      // projT[m][l], 3-term hi/lo split
      f32x4 pr[4] = {};
      __builtin_amdgcn_s_setprio(1);
#pragma unroll
      for (int kk = 0; kk < 2; ++kk) {
        const int cx = (kk * 32 + g * 8) ^ sx;
#pragma unroll
        for (int lf = 0; lf < 4; ++lf) {
          const bf16x8 bh2 = *(const bf16x8*)&KsHi[(lf * 16 + li) * 64 + cx];
          const bf16x8 bl2 = *(const bf16x8*)&KsLo[(lf * 16 + li) * 64 + cx];
          pr[lf] = mfma16(oh[p][kk], bh2, pr[lf]);
          pr[lf] = mfma16(oh[p][kk], bl2, pr[lf]);
          pr[lf] = mfma16(ol[p][kk], bh2, pr[lf]);
        }
      }
      __builtin_amdgcn_s_setprio(0);
      // phi (exp2) + ksum + KphiT (wave-private rows, swizzled)
#pragma unroll
      for (int lf = 0; lf < 4; ++lf) {
        const float nrm = ns[lf * 16 + li];
#pragma unroll
        for (int r = 0; r < 4; ++r) {
          float phi = exp2f(pr[lf][r] - nrm) + EPSF;
          ksacc[p][r] += phi;
          const int row = w * 16 + 4 * g + r;
          KphiT[row * 64 + SWZ(row, lf * 16 + li)] = f2bf(phi);
        }
      }
      // kv += KphiT . V^T (same-wave LDS dependence, no barrier)
      __builtin_amdgcn_s_setprio(1);
#pragma unroll
      for (int kk = 0; kk < 2; ++kk) {
        const int cx = (kk * 32 + g * 8) ^ sx;
        const bf16x8 a = *(const bf16x8*)&KphiT[(w * 16 + li) * 64 + cx];
#pragma unroll
        for (int df = 0; df < 4; ++df) {
          const bf16x8 bv = *(const bf16x8*)&VT[(df * 16 + li) * 64 + cx];
          kvacc[p][df] = mfma16(a, bv, kvacc[p][df]);
        }
      }
      __builtin_amdgcn_s_setprio(0);
    }
  }
  float* kvo = pkv + ((size_t)sp * 64 + bh) * (MMF * DK);
#pragma unroll
  for (int p = 0; p < 4; ++p)
#pragma unroll
    for (int df = 0; df < 4; ++df)
#pragma unroll
      for (int r = 0; r < 4; ++r)
        kvo[(p * 64 + w * 16 + 4 * g + r) * DK + df * 16 + li] = kvacc[p][df][r];

  float* kso = pksum + ((size_t)sp * 64 + bh) * MMF;
#pragma unroll
  for (int p = 0; p < 4; ++p)
#pragma unroll
    for (int r = 0; r < 4; ++r) {
      float s = ksacc[p][r];
      s += __shfl_xor(s, 1); s += __shfl_xor(s, 2);
      s += __shfl_xor(s, 4); s += __shfl_xor(s, 8);
      if (li == 0) kso[p * 64 + w * 16 + 4 * g + r] = s;
    }
}

// ---------------------------------------------------------------------------
// reduce partials; emit kv TRANSPOSED bf16 kvT[bh][d][m] + ksum fp32
// ---------------------------------------------------------------------------
__global__ __launch_bounds__(256) void reduce_parts(
    const float* __restrict__ pkv, unsigned short* __restrict__ kvT,
    const float* __restrict__ pks, float* __restrict__ ksg) {
  const int id = blockIdx.x * 256 + threadIdx.x;   // grid 1024 -> 262144
  {
    const int bh = id >> 12, rest = id & 4095;
    const int m0 = (rest >> 6) << 2, d = rest & 63;
    float s0 = 0.f, s1 = 0.f, s2 = 0.f, s3 = 0.f;
#pragma unroll
    for (int sp = 0; sp < NSPLIT; ++sp) {
      const float* p = pkv + (size_t)(sp * 64 + bh) * (MMF * DK) + d;
      s0 += p[(m0 + 0) * DK]; s1 += p[(m0 + 1) * DK];
      s2 += p[(m0 + 2) * DK]; s3 += p[(m0 + 3) * DK];
    }
    ushort4 o;
    o.x = f2bf(s0); o.y = f2bf(s1); o.z = f2bf(s2); o.w = f2bf(s3);
    *(ushort4*)&kvT[((size_t)bh * DK + d) * MMF + m0] = o;
  }
  if (id < 4096) {
    float4 s = {0.f, 0.f, 0.f, 0.f};
#pragma unroll
    for (int sp = 0; sp < NSPLIT; ++sp) {
      float4 v = *(const float4*)&pks[(size_t)sp * 64 * MMF + id * 4];
      s.x += v.x; s.y += v.y; s.z += v.z; s.w += v.w;
    }
    *(float4*)&ksg[id * 4] = s;
  }
}

// ---------------------------------------------------------------------------
// q_phi + num/den -> attn (bf16). grid (64 bh, 32 l-blocks), 512 threads.
// 2-term proj split (orf-lo dropped). Q frags / norms / ksums in registers;
// OHi + kvT resident in LDS (80KB exactly -> 2 blocks/CU); barrier-free loop.
// ---------------------------------------------------------------------------
__global__ __launch_bounds__(512, 4) void qattn_mfma(
    const unsigned short* __restrict__ qhi, const unsigned short* __restrict__ qlo,
    const float* __restrict__ qnorms,
    const unsigned short* __restrict__ orfhi,
    const unsigned short* __restrict__ kvT, const float* __restrict__ ksg,
    unsigned short* __restrict__ attn) {
  __shared__ __align__(16) unsigned short OHi[256 * 64];    // 32 KB
  __shared__ __align__(16) unsigned short KvTs[64 * 256];   // 32 KB
  __shared__ __align__(16) unsigned short Qphi[8][16 * 64]; // 16 KB  -> 80 KB total
  const int tid = threadIdx.x, lane = tid & 63, w = tid >> 6;   // w: 0..7
  const int g = lane >> 4, li = lane & 15;
  const int bh = blockIdx.x, lb = blockIdx.y;
  const int b = bh >> 4, h = bh & 15;
  const int srow8 = lane >> 3;
  const int scol  = ((lane & 7) ^ srow8) << 3;
  const int sx = (li & 7) << 3;

  // ---- one-time staging ----
#pragma unroll
  for (int q = 0; q < 4; ++q) {   // orf-hi: wave w stages rows w*32 .. w*32+31
    const size_t o = (size_t)(w * 32 + q * 8 + srow8) * 64 + scol;
    gload16(orfhi + o, &OHi[(w * 32 + q * 8) * 64]);
  }
  {  // kvT: 64 rows x 512B; 2 rows per gload; wave w stages rows w*8..w*8+7
    const int srow2 = lane >> 5;                  // 0..1
#pragma unroll
    for (int q = 0; q < 4; ++q) {
      const int d0 = w * 8 + q * 2, dr = d0 + srow2;
      gload16(kvT + ((size_t)bh * DK + dr) * MMF + (((lane & 31) ^ (dr & 7)) << 3),
              &KvTs[d0 * 256]);
    }
  }

  // registers: ksums, norms, Q fragments
  float ksr[4][4];
#pragma unroll
  for (int p = 0; p < 4; ++p)
#pragma unroll
    for (int mf = 0; mf < 4; ++mf)
      ksr[p][mf] = ksg[(size_t)bh * MMF + p * 64 + mf * 16 + li];
  const float4 nr =
      *(const float4*)&qnorms[(size_t)bh * 4096 + lb * 128 + w * 16 + 4 * g];
  bf16x8 qh[2], ql[2];
  {
    const size_t qr = ((size_t)bh * 4096 + lb * 128 + w * 16 + li) * 64 + g * 8;
    qh[0] = *(const bf16x8*)&qhi[qr];
    qh[1] = *(const bf16x8*)&qhi[qr + 32];
    ql[0] = *(const bf16x8*)&qlo[qr];
    ql[1] = *(const bf16x8*)&qlo[qr + 32];
  }
  __syncthreads();   // gload staging complete

  f32x4 numacc[4] = {};
  float denacc[4] = {};

#pragma unroll
  for (int p = 0; p < 4; ++p) {
    // proj[l][m], 2-term split (qh*oh + ql*oh)
    f32x4 pr[4] = {};
    __builtin_amdgcn_s_setprio(1);
#pragma unroll
    for (int kk = 0; kk < 2; ++kk) {
      const int cx = (kk * 32 + g * 8) ^ sx;
#pragma unroll
      for (int mf = 0; mf < 4; ++mf) {
        const int row = p * 64 + mf * 16 + li;
        const bf16x8 bh2 = *(const bf16x8*)&OHi[row * 64 + cx];
        pr[mf] = mfma16(qh[kk], bh2, pr[mf]);
        pr[mf] = mfma16(ql[kk], bh2, pr[mf]);
      }
    }
    __builtin_amdgcn_s_setprio(0);
    // phi (exp2), den partial, Qphi (wave-private, swizzled)
#pragma unroll
    for (int mf = 0; mf < 4; ++mf) {
      const float ks = ksr[p][mf];
#pragma unroll
      for (int r = 0; r < 4; ++r) {
        float phi = exp2f(pr[mf][r] - nr[r]) + EPSF;
        denacc[r] += phi * ks;
        const int row = 4 * g + r;
        Qphi[w][row * 64 + SWZ(row, mf * 16 + li)] = f2bf(phi);
      }
    }
    // num += Qphi . kvT (same-wave Qphi; KvTs stable)
    __builtin_amdgcn_s_setprio(1);
#pragma unroll
    for (int kk = 0; kk < 2; ++kk) {
      const int cx = (kk * 32 + g * 8) ^ sx;
      const bf16x8 a = *(const bf16x8*)&Qphi[w][li * 64 + cx];
#pragma unroll
      for (int df = 0; df < 4; ++df) {
        const bf16x8 bv = *(const bf16x8*)
            &KvTs[(df * 16 + li) * 256 + (((p * 8 + kk * 4 + g) ^ (li & 7)) << 3)];
        numacc[df] = mfma16(a, bv, numacc[df]);
      }
    }
    __builtin_amdgcn_s_setprio(0);
  }
  float den[4];
#pragma unroll
  for (int r = 0; r < 4; ++r) {
    float s = denacc[r];
    s += __shfl_xor(s, 1); s += __shfl_xor(s, 2);
    s += __shfl_xor(s, 4); s += __shfl_xor(s, 8);
    den[r] = s;
  }
  unsigned short* ab =
      attn + ((size_t)b * 4096 + lb * 128) * 1024 + h * 64;
#pragma unroll
  for (int df = 0; df < 4; ++df)
#pragma unroll
    for (int r = 0; r < 4; ++r)
      ab[(size_t)(w * 16 + 4 * g + r) * 1024 + df * 16 + li] =
          f2bf(numacc[df][r] / den[r]);
}

// ---------------------------------------------------------------------------
extern "C" void kernel_launch(void* const* d_in, const int* in_sizes, int n_in,
                              void* d_out, int out_size, void* d_ws, size_t ws_size,
                              hipStream_t stream) {
  (void)in_sizes; (void)n_in; (void)out_size; (void)ws_size;
  const float* x   = (const float*)d_in[0];
  const float* Wq  = (const float*)d_in[1];
  const float* bq  = (const float*)d_in[2];
  const float* Wk  = (const float*)d_in[3];
  const float* bk  = (const float*)d_in[4];
  const float* Wv  = (const float*)d_in[5];
  const float* bv  = (const float*)d_in[6];
  const float* Wo  = (const float*)d_in[7];
  const float* bo  = (const float*)d_in[8];
  const float* orf = (const float*)d_in[9];
  float* out = (float*)d_out;

  const size_t ND = (size_t)BB * LL * DD;   // 16,777,216
  char* base = (char*)d_ws;
  size_t off = 0;
  auto alloc = [&](size_t bytes) -> char* {
    char* p = base + off;
    off += (bytes + 255) & ~(size_t)255;
    return p;
  };
  unsigned short* wqbf   = (unsigned short*)alloc((size_t)DD * DD * 2);
  unsigned short* wkbf   = (unsigned short*)alloc((size_t)DD * DD * 2);
  unsigned short* wvbf   = (unsigned short*)alloc((size_t)DD * DD * 2);
  unsigned short* wobf   = (unsigned short*)alloc((size_t)DD * DD * 2);
  unsigned short* orfhi  = (unsigned short*)alloc((size_t)MMF * DK * 2);
  unsigned short* orflo  = (unsigned short*)alloc((size_t)MMF * DK * 2);
  unsigned short* xbf    = (unsigned short*)alloc(ND * 2);   // aliased by pkv
  unsigned short* qhi    = (unsigned short*)alloc(ND * 2);
  unsigned short* qlo    = (unsigned short*)alloc(ND * 2);
  unsigned short* khi    = (unsigned short*)alloc(ND * 2);   // aliased by attnbf
  unsigned short* klo    = (unsigned short*)alloc(ND * 2);
  unsigned short* vtbuf  = (unsigned short*)alloc(ND * 2);
  float*          qnorms = (float*)alloc((size_t)64 * LL * 4);
  float*          knorms = (float*)alloc((size_t)64 * LL * 4);
  float*          pksum  = (float*)alloc((size_t)NSPLIT * 64 * MMF * 4);
  unsigned short* kvT    = (unsigned short*)alloc((size_t)64 * DK * MMF * 2);
  float*          ksg    = (float*)alloc((size_t)64 * MMF * 4);
  float*          pkv    = (float*)xbf;            // 33.5 MB, exact alias
  unsigned short* attnbf = khi;                    // khi dead after kv_mfma

  cvt_bf16<<<16384, 256, 0, stream>>>(x, xbf, (int)ND);
  cvt_bf16_w<<<dim3(1024, 4), 256, 0, stream>>>(Wq, Wk, Wv, Wo,
                                                wqbf, wkbf, wvbf, wobf);
  cvt_orf<<<64, 256, 0, stream>>>(orf, orfhi, orflo, MMF * DK);

  dim3 gg(128, 8);
  gemm_mfma<2><<<gg, 256, 0, stream>>>(xbf, wqbf, bq, (float*)0, qhi, qlo,
                                       qnorms, BB * LL, DD, DD);
  gemm_mfma<2><<<gg, 256, 0, stream>>>(xbf, wkbf, bk, (float*)0, khi, klo,
                                       knorms, BB * LL, DD, DD);
  gemm_mfma<1><<<gg, 256, 0, stream>>>(xbf, wvbf, bv, (float*)0, vtbuf,
                                       (unsigned short*)0, (float*)0,
                                       BB * LL, DD, DD);

  kv_mfma<<<dim3(64, NSPLIT), 256, 0, stream>>>(khi, klo, knorms, vtbuf,
                                                orfhi, orflo, pkv, pksum);
  reduce_parts<<<1024, 256, 0, stream>>>(pkv, kvT, pksum, ksg);
  qattn_mfma<<<dim3(64, 32), 512, 0, stream>>>(qhi, qlo, qnorms, orfhi,
                                               kvT, ksg, attnbf);

  gemm_mfma<0><<<gg, 256, 0, stream>>>(attnbf, wobf, bo, out, (unsigned short*)0,
                                       (unsigned short*)0, (float*)0,
                                       BB * LL, DD, DD);
}

// Round 7
// 312.922 us; speedup vs baseline: 7.6828x; 1.0927x over previous
//
#include <hip/hip_runtime.h>
#include <math.h>

// Problem constants
#define HH 16
#define BB 4
#define LL 4096
#define DD 1024
#define DK 64
#define MMF 256
#define EPSF 1e-6f
// orf scale: 64^-0.25 * log2(e)  (phi computed as exp2)
#define KSCALE (0.35355339059327373f * 1.4426950408889634f)
// norm scale: 1/(2*sqrt(64)) * log2(e)
#define NORMSCALE (0.0625f * 1.4426950408889634f)
#define NSPLIT 8
#define LCH (LL / NSPLIT)             // 512 rows of L per kv block

typedef __attribute__((ext_vector_type(8))) short bf16x8;
typedef __attribute__((ext_vector_type(4))) float f32x4;
typedef __attribute__((ext_vector_type(8))) unsigned short u16x8;

__device__ __forceinline__ unsigned short f2bf(float f) {
  union { float f; unsigned u; } v; v.f = f;
  unsigned r = v.u + 0x7FFF + ((v.u >> 16) & 1);   // RNE
  return (unsigned short)(r >> 16);
}
__device__ __forceinline__ float bf2f(unsigned short h) {
  union { unsigned u; float f; } v; v.u = ((unsigned)h) << 16;
  return v.f;
}
__device__ __forceinline__ f32x4 mfma16(bf16x8 a, bf16x8 b, f32x4 c) {
  return __builtin_amdgcn_mfma_f32_16x16x32_bf16(a, b, c, 0, 0, 0);
}
// async global->LDS, 16B per lane; dst is wave-uniform base (lane x16 implicit)
__device__ __forceinline__ void gload16(const unsigned short* g, unsigned short* l) {
  __builtin_amdgcn_global_load_lds(
      (const __attribute__((address_space(1))) void*)g,
      (__attribute__((address_space(3))) void*)l, 16, 0, 0);
}
// T2 swizzle for 64-element bf16 rows (element-index xor)
#define SWZ(row, col) ((col) ^ (((row) & 7) << 3))

// ---------------------------------------------------------------------------
// fp32 -> bf16 conversion (n multiple of 4)
// ---------------------------------------------------------------------------
__global__ __launch_bounds__(256) void cvt_bf16(
    const float* __restrict__ src, unsigned short* __restrict__ dst, int n) {
  int i = (blockIdx.x * 256 + threadIdx.x) * 4;
  if (i < n) {
    float4 v = *(const float4*)&src[i];
    ushort4 o;
    o.x = f2bf(v.x); o.y = f2bf(v.y); o.z = f2bf(v.z); o.w = f2bf(v.w);
    *(ushort4*)&dst[i] = o;
  }
}

// fused 4-way weight conversion, grid (1024, 4)
__global__ __launch_bounds__(256) void cvt_bf16_w(
    const float* __restrict__ W0, const float* __restrict__ W1,
    const float* __restrict__ W2, const float* __restrict__ W3,
    unsigned short* __restrict__ D0, unsigned short* __restrict__ D1,
    unsigned short* __restrict__ D2, unsigned short* __restrict__ D3) {
  const float* s;
  unsigned short* d;
  switch (blockIdx.y) {
    case 0: s = W0; d = D0; break;
    case 1: s = W1; d = D1; break;
    case 2: s = W2; d = D2; break;
    default: s = W3; d = D3; break;
  }
  int i = (blockIdx.x * 256 + threadIdx.x) * 4;
  float4 v = *(const float4*)&s[i];
  ushort4 o;
  o.x = f2bf(v.x); o.y = f2bf(v.y); o.z = f2bf(v.z); o.w = f2bf(v.w);
  *(ushort4*)&d[i] = o;
}

// orf: scale by KSCALE (dk^-.25 * log2e), split hi/lo bf16
__global__ __launch_bounds__(256) void cvt_orf(
    const float* __restrict__ src, unsigned short* __restrict__ hi,
    unsigned short* __restrict__ lo, int n) {
  int i = blockIdx.x * 256 + threadIdx.x;
  if (i < n) {
    float f = src[i] * KSCALE;
    unsigned short h = f2bf(f);
    hi[i] = h;
    lo[i] = f2bf(f - bf2f(h));
  }
}

// ---------------------------------------------------------------------------
// bf16 MFMA GEMM: C = A[M,K] @ W[N,K]^T + bias. 128x128 tile, BK=64, 4 waves.
// DOUBLE-BUFFERED LDS + counted vmcnt: next tile's 8 global_load_lds stay in
// flight across the compute phase (raw s_barrier; no vmcnt(0) drain in loop).
// Fixed shape M=16384, N=1024 -> grid 128x8, XCD-swizzled.
// Epilogue: per-wave LDS-transpose -> fully coalesced 16B vector stores.
// MODE 0: fp32 C row-major.
// MODE 1: bf16 transposed Ct[(b*16+h)*64+d][4096]                  (V path)
// MODE 2: hi/lo bf16 [bh][l][64] + norms[bh][l] (pre *log2e/16)    (Q,K paths)
// ---------------------------------------------------------------------------
template <int MODE>
__global__ __launch_bounds__(256) void gemm_mfma(
    const unsigned short* __restrict__ A, const unsigned short* __restrict__ W,
    const float* __restrict__ bias, float* __restrict__ Cf,
    unsigned short* __restrict__ C1, unsigned short* __restrict__ C2,
    float* __restrict__ Cn, int M, int N, int K) {
  // [A0 16KB | B0 16KB | A1 16KB | B1 16KB]; epilogue reuses front 34816 B
  __shared__ __align__(16) char smem[65536];
  unsigned short* S = (unsigned short*)smem;
  const int tid = threadIdx.x, lane = tid & 63;
  const int w = tid >> 6, wr = w >> 1, wc = w & 1;
  const int g = lane >> 4, li = lane & 15;
  // XCD swizzle: each XCD owns 16 contiguous M-panels x all 8 N-panels
  const int flat = blockIdx.y * gridDim.x + blockIdx.x;     // 0..1023
  const int xcd = flat & 7, loc = flat >> 3;
  const int m0 = ((xcd << 4) + (loc & 15)) * 128;
  const int n0 = (loc >> 4) * 128;

  f32x4 acc[4][4] = {};
  const int srow8 = lane >> 3;                    // row within 8-row group
  const int scol  = ((lane & 7) ^ srow8) << 3;    // pre-swizzled element col
  const unsigned short* Ag = A + (size_t)(m0 + w * 32 + srow8) * K + scol;
  const unsigned short* Wg = W + (size_t)(n0 + w * 32 + srow8) * K + scol;
  const int nt = K >> 6;

  // prologue: stage tile 0 into buffer 0
#pragma unroll
  for (int j = 0; j < 4; ++j) {
    gload16(Ag + (size_t)j * 8 * K, S + (w * 32 + j * 8) * 64);
    gload16(Wg + (size_t)j * 8 * K, S + 8192 + (w * 32 + j * 8) * 64);
  }

  for (int t = 0; t < nt; ++t) {
    const int co = (t & 1) << 14;           // current buffer (ushort offset)
    const int no = co ^ 16384;              // next buffer
    if (t + 1 < nt) {
      const int k1 = (t + 1) << 6;
#pragma unroll
      for (int j = 0; j < 4; ++j) {
        gload16(Ag + (size_t)j * 8 * K + k1, S + no + (w * 32 + j * 8) * 64);
        gload16(Wg + (size_t)j * 8 * K + k1, S + no + 8192 + (w * 32 + j * 8) * 64);
      }
      // wait only for the CURRENT tile's 8 loads; next 8 stay in flight
      asm volatile("s_waitcnt vmcnt(8)" ::: "memory");
    } else {
      asm volatile("s_waitcnt vmcnt(0)" ::: "memory");
    }
    __builtin_amdgcn_s_barrier();

    const int sx = (li & 7) << 3;
#pragma unroll
    for (int kk = 0; kk < 2; ++kk) {
      const int c = (kk * 32 + g * 8) ^ sx;
      bf16x8 af[4], bfr[4];
#pragma unroll
      for (int i = 0; i < 4; ++i)
        af[i] = *(const bf16x8*)&S[co + (wr * 64 + i * 16 + li) * 64 + c];
#pragma unroll
      for (int j = 0; j < 4; ++j)
        bfr[j] = *(const bf16x8*)&S[co + 8192 + (wc * 64 + j * 16 + li) * 64 + c];
#pragma unroll
      for (int i = 0; i < 4; ++i)
#pragma unroll
        for (int j = 0; j < 4; ++j)
          acc[i][j] = mfma16(af[i], bfr[j], acc[i][j]);
    }
    // ds_reads must COMPLETE before next iteration re-stages this buffer
    asm volatile("s_waitcnt lgkmcnt(0)" ::: "memory");
    __builtin_amdgcn_s_barrier();
  }

  // ---------------- epilogue: LDS transpose, coalesced stores ---------------
  float* ep = (float*)smem + w * (32 * 68);
  const int head = (n0 + wc * 64) >> 6;
  const int rbase = m0 + wr * 64;       // global row base of this wave's tile
  const int b = rbase >> 12;            // batch (tile never crosses b boundary)

  if (MODE == 2) {
#pragma unroll
    for (int jh = 0; jh < 2; ++jh) {
      // write half: local rows 0..31 = global rows jh*32..+31, all 64 cols
#pragma unroll
      for (int i2 = 0; i2 < 2; ++i2) {
        const int i = jh * 2 + i2;
#pragma unroll
        for (int j = 0; j < 4; ++j) {
          const float bz = bias[n0 + wc * 64 + j * 16 + li];
#pragma unroll
          for (int r = 0; r < 4; ++r)
            ep[(i2 * 16 + 4 * g + r) * 68 + j * 16 + li] = acc[i][j][r] + bz;
        }
      }
      // read half: lane -> (row = p*8 + lane>>3, chunk c = lane&7 of 8 f32)
      const int rrow = lane >> 3, cc = lane & 7;
#pragma unroll
      for (int p = 0; p < 4; ++p) {
        const int row = p * 8 + rrow;
        float v[8];
        *(f32x4*)&v[0] = *(const f32x4*)&ep[row * 68 + cc * 8];
        *(f32x4*)&v[4] = *(const f32x4*)&ep[row * 68 + cc * 8 + 4];
        float np = 0.f;
        u16x8 hv, lv;
#pragma unroll
        for (int e = 0; e < 8; ++e) {
          float vv = v[e];
          np += vv * vv;
          unsigned short h = f2bf(vv);
          hv[e] = h;
          lv[e] = f2bf(vv - bf2f(h));
        }
        const int lg = (rbase + jh * 32 + row) & 4095;
        const size_t rowb = (size_t)(b * 16 + head) * 4096 + lg;
        *(u16x8*)&C1[rowb * 64 + cc * 8] = hv;
        *(u16x8*)&C2[rowb * 64 + cc * 8] = lv;
        np += __shfl_xor(np, 1);
        np += __shfl_xor(np, 2);
        np += __shfl_xor(np, 4);
        if (cc == 0) Cn[rowb] = np * NORMSCALE;
      }
    }
  } else if (MODE == 1) {
#pragma unroll
    for (int jh = 0; jh < 2; ++jh) {
      // write half: LDS [32 d][68 l]; acc's 4 rows (l) contiguous -> b128
#pragma unroll
      for (int i = 0; i < 4; ++i)
#pragma unroll
        for (int j2 = 0; j2 < 2; ++j2) {
          const int j = jh * 2 + j2;
          const float bz = bias[n0 + wc * 64 + j * 16 + li];
          f32x4 t;
          t[0] = acc[i][j][0] + bz; t[1] = acc[i][j][1] + bz;
          t[2] = acc[i][j][2] + bz; t[3] = acc[i][j][3] + bz;
          *(f32x4*)&ep[(j2 * 16 + li) * 68 + i * 16 + 4 * g] = t;
        }
      // read half: lane -> (d = p*8 + lane>>3, chunk c = lane&7 of 8 l)
      const int rd = lane >> 3, cc = lane & 7;
#pragma unroll
      for (int p = 0; p < 4; ++p) {
        const int dl = p * 8 + rd;
        float v[8];
        *(f32x4*)&v[0] = *(const f32x4*)&ep[dl * 68 + cc * 8];
        *(f32x4*)&v[4] = *(const f32x4*)&ep[dl * 68 + cc * 8 + 4];
        u16x8 hv;
#pragma unroll
        for (int e = 0; e < 8; ++e) hv[e] = f2bf(v[e]);
        const int dh = jh * 32 + dl;
        const int lg = rbase & 4095;
        *(u16x8*)&C1[((size_t)(b * 16 + head) * 64 + dh) * 4096 + lg + cc * 8] = hv;
      }
    }
  } else {  // MODE 0: fp32 row-major
#pragma unroll
    for (int jh = 0; jh < 2; ++jh) {
#pragma unroll
      for (int i2 = 0; i2 < 2; ++i2) {
        const int i = jh * 2 + i2;
#pragma unroll
        for (int j = 0; j < 4; ++j) {
          const float bz = bias[n0 + wc * 64 + j * 16 + li];
#pragma unroll
          for (int r = 0; r < 4; ++r)
            ep[(i2 * 16 + 4 * g + r) * 68 + j * 16 + li] = acc[i][j][r] + bz;
        }
      }
      // read: lane -> (row = p*4 + lane>>4, chunk c = lane&15 of 4 f32)
      const int rrow = lane >> 4, cc = lane & 15;
#pragma unroll
      for (int p = 0; p < 8; ++p) {
        const int row = p * 4 + rrow;
        f32x4 v = *(const f32x4*)&ep[row * 68 + cc * 4];
        *(f32x4*)&Cf[(size_t)(rbase + jh * 32 + row) * 1024 + n0 + wc * 64 + cc * 4] = v;
      }
    }
  }
}

// ---------------------------------------------------------------------------
// kv + ksum. grid (64 bh, NSPLIT). orf hi/lo fragments in REGISTERS (3-term
// split); K hi/lo, V^T staged via gload16; barrier-free 4-pass inner loop.
// ---------------------------------------------------------------------------
__global__ __launch_bounds__(256, 2) void kv_mfma(
    const unsigned short* __restrict__ khi, const unsigned short* __restrict__ klo,
    const float* __restrict__ knorms, const unsigned short* __restrict__ vt,
    const unsigned short* __restrict__ orfhi, const unsigned short* __restrict__ orflo,
    float* __restrict__ pkv, float* __restrict__ pksum) {
  __shared__ __align__(16) unsigned short KsHi[64 * 64], KsLo[64 * 64];
  __shared__ __align__(16) unsigned short VT[64 * 64], KphiT[64 * 64];
  __shared__ float ns[64];
  const int tid = threadIdx.x, lane = tid & 63, w = tid >> 6;
  const int g = lane >> 4, li = lane & 15;
  const int bh = blockIdx.x, sp = blockIdx.y;
  const int srow8 = lane >> 3;
  const int scol  = ((lane & 7) ^ srow8) << 3;
  const int sx = (li & 7) << 3;

  // orf fragments in registers: A-operand rows m = p*64 + w*16 + li
  bf16x8 oh[4][2], ol[4][2];
#pragma unroll
  for (int p = 0; p < 4; ++p)
#pragma unroll
    for (int kk = 0; kk < 2; ++kk) {
      const size_t o = (size_t)(p * 64 + w * 16 + li) * 64 + kk * 32 + g * 8;
      oh[p][kk] = *(const bf16x8*)&orfhi[o];
      ol[p][kk] = *(const bf16x8*)&orflo[o];
    }

  f32x4 kvacc[4][4] = {};
  float ksacc[4][4] = {};

  for (int c = 0; c < LCH / 64; ++c) {
    const int l0 = sp * LCH + c * 64;
    __syncthreads();   // previous chunk's readers done
    {  // stage K hi/lo + V^T via gload (pre-swizzled source, linear LDS)
      const size_t kb = ((size_t)bh * 4096 + l0 + w * 16 + srow8) * 64 + scol;
      gload16(khi + kb, &KsHi[(w * 16) * 64]);
      gload16(khi + kb + 8 * 64, &KsHi[(w * 16 + 8) * 64]);
      gload16(klo + kb, &KsLo[(w * 16) * 64]);
      gload16(klo + kb + 8 * 64, &KsLo[(w * 16 + 8) * 64]);
      const size_t vb = ((size_t)bh * 64 + w * 16 + srow8) * 4096 + l0 + scol;
      gload16(vt + vb, &VT[(w * 16) * 64]);
      gload16(vt + vb + (size_t)8 * 4096, &VT[(w * 16 + 8) * 64]);
      if (tid < 64) ns[tid] = knorms[(size_t)bh * 4096 + l0 + tid];
    }
    __syncthreads();

#pragma unroll
    for (int p = 0; p < 4; ++p) {
      // projT[m][l], 3-term hi/lo split
      f32x4 pr[4] = {};
      __builtin_amdgcn_s_setprio(1);
#pragma unroll
      for (int kk = 0; kk < 2; ++kk) {
        const int cx = (kk * 32 + g * 8) ^ sx;
#pragma unroll
        for (int lf = 0; lf < 4; ++lf) {
          const bf16x8 bh2 = *(const bf16x8*)&KsHi[(lf * 16 + li) * 64 + cx];
          const bf16x8 bl2 = *(const bf16x8*)&KsLo[(lf * 16 + li) * 64 + cx];
          pr[lf] = mfma16(oh[p][kk], bh2, pr[lf]);
          pr[lf] = mfma16(oh[p][kk], bl2, pr[lf]);
          pr[lf] = mfma16(ol[p][kk], bh2, pr[lf]);
        }
      }
      __builtin_amdgcn_s_setprio(0);
      // phi (exp2) + ksum + KphiT (wave-private rows, swizzled)
#pragma unroll
      for (int lf = 0; lf < 4; ++lf) {
        const float nrm = ns[lf * 16 + li];
#pragma unroll
        for (int r = 0; r < 4; ++r) {
          float phi = exp2f(pr[lf][r] - nrm) + EPSF;
          ksacc[p][r] += phi;
          const int row = w * 16 + 4 * g + r;
          KphiT[row * 64 + SWZ(row, lf * 16 + li)] = f2bf(phi);
        }
      }
      // kv += KphiT . V^T (same-wave LDS dependence, no barrier)
      __builtin_amdgcn_s_setprio(1);
#pragma unroll
      for (int kk = 0; kk < 2; ++kk) {
        const int cx = (kk * 32 + g * 8) ^ sx;
        const bf16x8 a = *(const bf16x8*)&KphiT[(w * 16 + li) * 64 + cx];
#pragma unroll
        for (int df = 0; df < 4; ++df) {
          const bf16x8 bv = *(const bf16x8*)&VT[(df * 16 + li) * 64 + cx];
          kvacc[p][df] = mfma16(a, bv, kvacc[p][df]);
        }
      }
      __builtin_amdgcn_s_setprio(0);
    }
  }
  float* kvo = pkv + ((size_t)sp * 64 + bh) * (MMF * DK);
#pragma unroll
  for (int p = 0; p < 4; ++p)
#pragma unroll
    for (int df = 0; df < 4; ++df)
#pragma unroll
      for (int r = 0; r < 4; ++r)
        kvo[(p * 64 + w * 16 + 4 * g + r) * DK + df * 16 + li] = kvacc[p][df][r];

  float* kso = pksum + ((size_t)sp * 64 + bh) * MMF;
#pragma unroll
  for (int p = 0; p < 4; ++p)
#pragma unroll
    for (int r = 0; r < 4; ++r) {
      float s = ksacc[p][r];
      s += __shfl_xor(s, 1); s += __shfl_xor(s, 2);
      s += __shfl_xor(s, 4); s += __shfl_xor(s, 8);
      if (li == 0) kso[p * 64 + w * 16 + 4 * g + r] = s;
    }
}

// ---------------------------------------------------------------------------
// reduce partials; emit kv TRANSPOSED bf16 kvT[bh][d][m] + ksum fp32
// ---------------------------------------------------------------------------
__global__ __launch_bounds__(256) void reduce_parts(
    const float* __restrict__ pkv, unsigned short* __restrict__ kvT,
    const float* __restrict__ pks, float* __restrict__ ksg) {
  const int id = blockIdx.x * 256 + threadIdx.x;   // grid 1024 -> 262144
  {
    const int bh = id >> 12, rest = id & 4095;
    const int m0 = (rest >> 6) << 2, d = rest & 63;
    float s0 = 0.f, s1 = 0.f, s2 = 0.f, s3 = 0.f;
#pragma unroll
    for (int sp = 0; sp < NSPLIT; ++sp) {
      const float* p = pkv + (size_t)(sp * 64 + bh) * (MMF * DK) + d;
      s0 += p[(m0 + 0) * DK]; s1 += p[(m0 + 1) * DK];
      s2 += p[(m0 + 2) * DK]; s3 += p[(m0 + 3) * DK];
    }
    ushort4 o;
    o.x = f2bf(s0); o.y = f2bf(s1); o.z = f2bf(s2); o.w = f2bf(s3);
    *(ushort4*)&kvT[((size_t)bh * DK + d) * MMF + m0] = o;
  }
  if (id < 4096) {
    float4 s = {0.f, 0.f, 0.f, 0.f};
#pragma unroll
    for (int sp = 0; sp < NSPLIT; ++sp) {
      float4 v = *(const float4*)&pks[(size_t)sp * 64 * MMF + id * 4];
      s.x += v.x; s.y += v.y; s.z += v.z; s.w += v.w;
    }
    *(float4*)&ksg[id * 4] = s;
  }
}

// ---------------------------------------------------------------------------
// q_phi + num/den -> attn (bf16). grid (64 bh, 32 l-blocks), 512 threads.
// 2-term proj split (orf-lo dropped). Q frags / norms / ksums in registers;
// OHi + kvT resident in LDS (80KB exactly -> 2 blocks/CU); barrier-free loop.
// ---------------------------------------------------------------------------
__global__ __launch_bounds__(512, 4) void qattn_mfma(
    const unsigned short* __restrict__ qhi, const unsigned short* __restrict__ qlo,
    const float* __restrict__ qnorms,
    const unsigned short* __restrict__ orfhi,
    const unsigned short* __restrict__ kvT, const float* __restrict__ ksg,
    unsigned short* __restrict__ attn) {
  __shared__ __align__(16) unsigned short OHi[256 * 64];    // 32 KB
  __shared__ __align__(16) unsigned short KvTs[64 * 256];   // 32 KB
  __shared__ __align__(16) unsigned short Qphi[8][16 * 64]; // 16 KB  -> 80 KB total
  const int tid = threadIdx.x, lane = tid & 63, w = tid >> 6;   // w: 0..7
  const int g = lane >> 4, li = lane & 15;
  const int bh = blockIdx.x, lb = blockIdx.y;
  const int b = bh >> 4, h = bh & 15;
  const int srow8 = lane >> 3;
  const int scol  = ((lane & 7) ^ srow8) << 3;
  const int sx = (li & 7) << 3;

  // ---- one-time staging ----
#pragma unroll
  for (int q = 0; q < 4; ++q) {   // orf-hi: wave w stages rows w*32 .. w*32+31
    const size_t o = (size_t)(w * 32 + q * 8 + srow8) * 64 + scol;
    gload16(orfhi + o, &OHi[(w * 32 + q * 8) * 64]);
  }
  {  // kvT: 64 rows x 512B; 2 rows per gload; wave w stages rows w*8..w*8+7
    const int srow2 = lane >> 5;                  // 0..1
#pragma unroll
    for (int q = 0; q < 4; ++q) {
      const int d0 = w * 8 + q * 2, dr = d0 + srow2;
      gload16(kvT + ((size_t)bh * DK + dr) * MMF + (((lane & 31) ^ (dr & 7)) << 3),
              &KvTs[d0 * 256]);
    }
  }

  // registers: ksums, norms, Q fragments
  float ksr[4][4];
#pragma unroll
  for (int p = 0; p < 4; ++p)
#pragma unroll
    for (int mf = 0; mf < 4; ++mf)
      ksr[p][mf] = ksg[(size_t)bh * MMF + p * 64 + mf * 16 + li];
  const float4 nr =
      *(const float4*)&qnorms[(size_t)bh * 4096 + lb * 128 + w * 16 + 4 * g];
  bf16x8 qh[2], ql[2];
  {
    const size_t qr = ((size_t)bh * 4096 + lb * 128 + w * 16 + li) * 64 + g * 8;
    qh[0] = *(const bf16x8*)&qhi[qr];
    qh[1] = *(const bf16x8*)&qhi[qr + 32];
    ql[0] = *(const bf16x8*)&qlo[qr];
    ql[1] = *(const bf16x8*)&qlo[qr + 32];
  }
  __syncthreads();   // gload staging complete

  f32x4 numacc[4] = {};
  float denacc[4] = {};

#pragma unroll
  for (int p = 0; p < 4; ++p) {
    // proj[l][m], 2-term split (qh*oh + ql*oh)
    f32x4 pr[4] = {};
    __builtin_amdgcn_s_setprio(1);
#pragma unroll
    for (int kk = 0; kk < 2; ++kk) {
      const int cx = (kk * 32 + g * 8) ^ sx;
#pragma unroll
      for (int mf = 0; mf < 4; ++mf) {
        const int row = p * 64 + mf * 16 + li;
        const bf16x8 bh2 = *(const bf16x8*)&OHi[row * 64 + cx];
        pr[mf] = mfma16(qh[kk], bh2, pr[mf]);
        pr[mf] = mfma16(ql[kk], bh2, pr[mf]);
      }
    }
    __builtin_amdgcn_s_setprio(0);
    // phi (exp2), den partial, Qphi (wave-private, swizzled)
#pragma unroll
    for (int mf = 0; mf < 4; ++mf) {
      const float ks = ksr[p][mf];
#pragma unroll
      for (int r = 0; r < 4; ++r) {
        float phi = exp2f(pr[mf][r] - nr[r]) + EPSF;
        denacc[r] += phi * ks;
        const int row = 4 * g + r;
        Qphi[w][row * 64 + SWZ(row, mf * 16 + li)] = f2bf(phi);
      }
    }
    // num += Qphi . kvT (same-wave Qphi; KvTs stable)
    __builtin_amdgcn_s_setprio(1);
#pragma unroll
    for (int kk = 0; kk < 2; ++kk) {
      const int cx = (kk * 32 + g * 8) ^ sx;
      const bf16x8 a = *(const bf16x8*)&Qphi[w][li * 64 + cx];
#pragma unroll
      for (int df = 0; df < 4; ++df) {
        const bf16x8 bv = *(const bf16x8*)
            &KvTs[(df * 16 + li) * 256 + (((p * 8 + kk * 4 + g) ^ (li & 7)) << 3)];
        numacc[df] = mfma16(a, bv, numacc[df]);
      }
    }
    __builtin_amdgcn_s_setprio(0);
  }
  float den[4];
#pragma unroll
  for (int r = 0; r < 4; ++r) {
    float s = denacc[r];
    s += __shfl_xor(s, 1); s += __shfl_xor(s, 2);
    s += __shfl_xor(s, 4); s += __shfl_xor(s, 8);
    den[r] = s;
  }
  unsigned short* ab =
      attn + ((size_t)b * 4096 + lb * 128) * 1024 + h * 64;
#pragma unroll
  for (int df = 0; df < 4; ++df)
#pragma unroll
    for (int r = 0; r < 4; ++r)
      ab[(size_t)(w * 16 + 4 * g + r) * 1024 + df * 16 + li] =
          f2bf(numacc[df][r] / den[r]);
}

// ---------------------------------------------------------------------------
extern "C" void kernel_launch(void* const* d_in, const int* in_sizes, int n_in,
                              void* d_out, int out_size, void* d_ws, size_t ws_size,
                              hipStream_t stream) {
  (void)in_sizes; (void)n_in; (void)out_size; (void)ws_size;
  const float* x   = (const float*)d_in[0];
  const float* Wq  = (const float*)d_in[1];
  const float* bq  = (const float*)d_in[2];
  const float* Wk  = (const float*)d_in[3];
  const float* bk  = (const float*)d_in[4];
  const float* Wv  = (const float*)d_in[5];
  const float* bv  = (const float*)d_in[6];
  const float* Wo  = (const float*)d_in[7];
  const float* bo  = (const float*)d_in[8];
  const float* orf = (const float*)d_in[9];
  float* out = (float*)d_out;

  const size_t ND = (size_t)BB * LL * DD;   // 16,777,216
  char* base = (char*)d_ws;
  size_t off = 0;
  auto alloc = [&](size_t bytes) -> char* {
    char* p = base + off;
    off += (bytes + 255) & ~(size_t)255;
    return p;
  };
  unsigned short* wqbf   = (unsigned short*)alloc((size_t)DD * DD * 2);
  unsigned short* wkbf   = (unsigned short*)alloc((size_t)DD * DD * 2);
  unsigned short* wvbf   = (unsigned short*)alloc((size_t)DD * DD * 2);
  unsigned short* wobf   = (unsigned short*)alloc((size_t)DD * DD * 2);
  unsigned short* orfhi  = (unsigned short*)alloc((size_t)MMF * DK * 2);
  unsigned short* orflo  = (unsigned short*)alloc((size_t)MMF * DK * 2);
  unsigned short* xbf    = (unsigned short*)alloc(ND * 2);   // aliased by pkv
  unsigned short* qhi    = (unsigned short*)alloc(ND * 2);
  unsigned short* qlo    = (unsigned short*)alloc(ND * 2);
  unsigned short* khi    = (unsigned short*)alloc(ND * 2);   // aliased by attnbf
  unsigned short* klo    = (unsigned short*)alloc(ND * 2);
  unsigned short* vtbuf  = (unsigned short*)alloc(ND * 2);
  float*          qnorms = (float*)alloc((size_t)64 * LL * 4);
  float*          knorms = (float*)alloc((size_t)64 * LL * 4);
  float*          pksum  = (float*)alloc((size_t)NSPLIT * 64 * MMF * 4);
  unsigned short* kvT    = (unsigned short*)alloc((size_t)64 * DK * MMF * 2);
  float*          ksg    = (float*)alloc((size_t)64 * MMF * 4);
  float*          pkv    = (float*)xbf;            // 33.5 MB, exact alias
  unsigned short* attnbf = khi;                    // khi dead after kv_mfma

  cvt_bf16<<<16384, 256, 0, stream>>>(x, xbf, (int)ND);
  cvt_bf16_w<<<dim3(1024, 4), 256, 0, stream>>>(Wq, Wk, Wv, Wo,
                                                wqbf, wkbf, wvbf, wobf);
  cvt_orf<<<64, 256, 0, stream>>>(orf, orfhi, orflo, MMF * DK);

  dim3 gg(128, 8);
  gemm_mfma<2><<<gg, 256, 0, stream>>>(xbf, wqbf, bq, (float*)0, qhi, qlo,
                                       qnorms, BB * LL, DD, DD);
  gemm_mfma<2><<<gg, 256, 0, stream>>>(xbf, wkbf, bk, (float*)0, khi, klo,
                                       knorms, BB * LL, DD, DD);
  gemm_mfma<1><<<gg, 256, 0, stream>>>(xbf, wvbf, bv, (float*)0, vtbuf,
                                       (unsigned short*)0, (float*)0,
                                       BB * LL, DD, DD);

  kv_mfma<<<dim3(64, NSPLIT), 256, 0, stream>>>(khi, klo, knorms, vtbuf,
                                                orfhi, orflo, pkv, pksum);
  reduce_parts<<<1024, 256, 0, stream>>>(pkv, kvT, pksum, ksg);
  qattn_mfma<<<dim3(64, 32), 512, 0, stream>>>(qhi, qlo, qnorms, orfhi,
                                               kvT, ksg, attnbf);

  gemm_mfma<0><<<gg, 256, 0, stream>>>(attnbf, wobf, bo, out, (unsigned short*)0,
                                       (unsigned short*)0, (float*)0,
                                       BB * LL, DD, DD);
}